// Round 11
// baseline (935.963 us; speedup 1.0000x reference)
//
#include <hip/hip_runtime.h>
#include <float.h>
#include <stdint.h>

// DGCNN_Grouper forward on MI355X. B=8, N=2048, K=16, fp32.
// r8 architecture (best passing: 538us). Round 10 change: FPS level-1 is
// single-wave with coords RE-READ from LDS each iteration (interleaved,
// conflict-free b128) and only dl[32] in registers -> no spill possible.
// Stream-ordered dispatches only; no device-scope sync.

#define DI __device__ __forceinline__
DI float f_add(float a, float b) { return __fadd_rn(a, b); }
DI float f_sub(float a, float b) { return __fsub_rn(a, b); }
DI float f_mul(float a, float b) { return __fmul_rn(a, b); }

// ---------------------------------------------------------------------------
// 32-bit DPP wave reduces (6-step gfx9 pattern; validated r8-r10).
// ---------------------------------------------------------------------------
template<int CTRL, int RMASK>
DI uint32_t dpp_umax32(uint32_t v) {
  uint32_t o = (uint32_t)__builtin_amdgcn_update_dpp(0, (int)v, CTRL, RMASK, 0xF, false);
  return v > o ? v : o;
}
template<int CTRL, int RMASK>
DI uint32_t dpp_umin32(uint32_t v) {
  uint32_t o = (uint32_t)__builtin_amdgcn_update_dpp(-1, (int)v, CTRL, RMASK, 0xF, false);
  return v < o ? v : o;
}
template<int CTRL, int RMASK>
DI float dpp_fmin32(float v) {
  int o = __builtin_amdgcn_update_dpp(0x7F7FFFFF /*FLT_MAX*/, __float_as_int(v),
                                      CTRL, RMASK, 0xF, false);
  return fminf(v, __int_as_float(o));
}
DI uint32_t wave_umax_bcast32(uint32_t v) {
  v = dpp_umax32<0x111, 0xF>(v);
  v = dpp_umax32<0x112, 0xF>(v);
  v = dpp_umax32<0x114, 0xF>(v);
  v = dpp_umax32<0x118, 0xF>(v);
  v = dpp_umax32<0x142, 0xA>(v);
  v = dpp_umax32<0x143, 0xC>(v);
  return (uint32_t)__builtin_amdgcn_readlane((int)v, 63);
}
DI uint32_t wave_umin_bcast32(uint32_t v) {
  v = dpp_umin32<0x111, 0xF>(v);
  v = dpp_umin32<0x112, 0xF>(v);
  v = dpp_umin32<0x114, 0xF>(v);
  v = dpp_umin32<0x118, 0xF>(v);
  v = dpp_umin32<0x142, 0xA>(v);
  v = dpp_umin32<0x143, 0xC>(v);
  return (uint32_t)__builtin_amdgcn_readlane((int)v, 63);
}
DI float wave_fmin_bcast32(float v) {
  v = dpp_fmin32<0x111, 0xF>(v);
  v = dpp_fmin32<0x112, 0xF>(v);
  v = dpp_fmin32<0x114, 0xF>(v);
  v = dpp_fmin32<0x118, 0xF>(v);
  v = dpp_fmin32<0x142, 0xA>(v);
  v = dpp_fmin32<0x143, 0xC>(v);
  return __int_as_float(__builtin_amdgcn_readlane(__float_as_int(v), 63));
}

// ---------------------------------------------------------------------------
// kNN (r8 verbatim): 16 smallest d2; f32-min phase + u32-min index phase.
// ---------------------------------------------------------------------------
template<int NK>
DI void knn_body(const float* __restrict__ cq, int Nq,
                 const float* __restrict__ ck, int* __restrict__ out,
                 int b, int qbase, float* smem)
{
  constexpr int CPL = NK / 64;
  float* xs = smem;
  float* ys = smem + NK;
  float* zs = smem + 2*NK;
  float* rr = smem + 3*NK;
  const int tid = threadIdx.x;
  for (int i = tid; i < NK; i += 256) {
    float a  = ck[((size_t)b*3 + 0)*NK + i];
    float bb = ck[((size_t)b*3 + 1)*NK + i];
    float c  = ck[((size_t)b*3 + 2)*NK + i];
    xs[i] = a; ys[i] = bb; zs[i] = c;
    rr[i] = f_add(f_add(f_mul(a,a), f_mul(bb,bb)), f_mul(c,c));
  }
  __syncthreads();
  const int lane = tid & 63, w = tid >> 6;
  const int q = qbase + w;
  if (q >= Nq) return;
  float qx = cq[((size_t)b*3 + 0)*Nq + q];
  float qy = cq[((size_t)b*3 + 1)*Nq + q];
  float qz = cq[((size_t)b*3 + 2)*Nq + q];
  float qq = f_add(f_add(f_mul(qx,qx), f_mul(qy,qy)), f_mul(qz,qz));
  float v[CPL];
  #pragma unroll
  for (int j = 0; j < CPL; ++j) {
    int c = j*64 + lane;
    float dot = f_add(f_add(f_mul(qx,xs[c]), f_mul(qy,ys[c])), f_mul(qz,zs[c]));
    v[j] = f_sub(f_add(qq, rr[c]), f_mul(2.0f, dot));
  }
  unsigned mask = (CPL >= 32) ? 0xFFFFFFFFu : ((1u << CPL) - 1u);
  for (int r = 0; r < 16; ++r) {
    float bv = FLT_MAX; int bc = 0x7FFFFFFF;
    #pragma unroll
    for (int j = 0; j < CPL; ++j) {
      float vj = ((mask >> j) & 1u) ? v[j] : FLT_MAX;
      if (vj < bv) { bv = vj; bc = j*64 + lane; }
    }
    float wmin = wave_fmin_bcast32(bv);
    uint32_t cand = (bv == wmin) ? (uint32_t)bc : 0xFFFFFFFFu;
    uint32_t wbc = wave_umin_bcast32(cand);
    if ((wbc & 63) == (uint32_t)lane) mask &= ~(1u << (wbc >> 6));
    if (lane == 0) out[((size_t)b*16 + r)*Nq + q] = (int)wbc;
  }
}

// ---------------------------------------------------------------------------
// FPS. Level 1: single wave, 32 pts/lane INTERLEAVED (idx = j*64+lane).
// Coords re-read from LDS each iteration (consecutive-lane b128 reads:
// conflict-free); only dl[32] lives in registers -> no spill. Strict-> scan
// (lowest j wins ties in-lane) + u32-umin over global idx across lanes =
// exact first-occurrence argmax. Level 2: r8-verbatim.
// ---------------------------------------------------------------------------
__device__ void fps_body(const float* __restrict__ x, int b,
                         int* __restrict__ s1, float* __restrict__ coorq,
                         int* __restrict__ s2, float* __restrict__ coorq2,
                         float* __restrict__ outc, char* smem_raw)
{
  float4* pts = (float4*)smem_raw;            // [2048]
  int*    sel = (int*)(smem_raw + 32768);     // [512]
  const int tid = threadIdx.x, lane = tid & 63, w = tid >> 6;

  for (int i = tid; i < 2048; i += 256)
    pts[i] = make_float4(x[((size_t)b*3 + 0)*2048 + i],
                         x[((size_t)b*3 + 1)*2048 + i],
                         x[((size_t)b*3 + 2)*2048 + i], 0.f);
  __syncthreads();

  if (w == 0) {
    // Level 1: 2048 -> 512.
    float dl[32];
    #pragma unroll
    for (int j = 0; j < 32; ++j) dl[j] = 1e10f;
    int far = 0;
    float4 c = pts[0];
    for (int i = 0; i < 512; ++i) {
      if (lane == 0) sel[i] = far;
      float bd = -1.0f; uint32_t bi = 0;
      #pragma unroll
      for (int j = 0; j < 32; ++j) {
        float4 p = pts[j*64 + lane];        // conflict-free wide LDS read
        float dx = f_sub(p.x, c.x);
        float dy = f_sub(p.y, c.y);
        float dz = f_sub(p.z, c.z);
        float d  = f_add(f_add(f_mul(dx,dx), f_mul(dy,dy)), f_mul(dz,dz));
        float nd = fminf(dl[j], d);
        dl[j] = nd;
        if (nd > bd) { bd = nd; bi = (uint32_t)(j*64 + lane); }
      }
      uint32_t db = __float_as_uint(bd);          // bd >= +0 => u32 order == f32
      uint32_t wd = wave_umax_bcast32(db);
      uint32_t cand = (db == wd) ? bi : 0xFFFFFFFFu;
      uint32_t wi = wave_umin_bcast32(cand);      // min global idx among ties
      far = (int)wi;
      c = pts[far];
    }
  }
  __syncthreads();

  // Dump level 1; bounce selected points into pts[0..511].
  int p0 = sel[tid], p1 = sel[tid + 256];
  float4 v0 = pts[p0], v1 = pts[p1];
  s1[b*512 + tid]       = p0;
  s1[b*512 + tid + 256] = p1;
  coorq[((size_t)b*3 + 0)*512 + tid] = v0.x;
  coorq[((size_t)b*3 + 1)*512 + tid] = v0.y;
  coorq[((size_t)b*3 + 2)*512 + tid] = v0.z;
  coorq[((size_t)b*3 + 0)*512 + tid + 256] = v1.x;
  coorq[((size_t)b*3 + 1)*512 + tid + 256] = v1.y;
  coorq[((size_t)b*3 + 2)*512 + tid + 256] = v1.z;
  __syncthreads();               // all pts reads complete before overwrite
  pts[tid] = v0; pts[tid + 256] = v1;
  __syncthreads();

  // Level 2: 512 -> 128 (r8 verbatim).
  if (w == 0) {
    float qx[8], qy[8], qz[8], d2[8];
    #pragma unroll
    for (int j = 0; j < 8; ++j) {
      float4 p = pts[lane + 64*j];
      qx[j] = p.x; qy[j] = p.y; qz[j] = p.z; d2[j] = 1e10f;
    }
    int far2 = 0;
    float cx = pts[0].x, cy = pts[0].y, cz = pts[0].z;
    for (int i = 0; i < 128; ++i) {
      if (lane == 0) sel[i] = far2;
      float bd = -1.0f; uint32_t bi = 0;
      #pragma unroll
      for (int j = 0; j < 8; ++j) {
        float dx = f_sub(qx[j], cx);
        float dy = f_sub(qy[j], cy);
        float dz = f_sub(qz[j], cz);
        float d  = f_add(f_add(f_mul(dx,dx), f_mul(dy,dy)), f_mul(dz,dz));
        float nd = fminf(d2[j], d);
        d2[j] = nd;
        if (nd > bd) { bd = nd; bi = (uint32_t)(lane + 64*j); }
      }
      uint32_t db = __float_as_uint(bd);
      uint32_t wd = wave_umax_bcast32(db);
      uint32_t cand = (db == wd) ? bi : 0xFFFFFFFFu;
      uint32_t wi = wave_umin_bcast32(cand);
      far2 = (int)wi;
      uint32_t js = wi >> 6, ls = wi & 63;
      float sx = qx[0], sy = qy[0], sz = qz[0];
      #pragma unroll
      for (uint32_t t = 1; t < 8; ++t) {
        sx = (js == t) ? qx[t] : sx;
        sy = (js == t) ? qy[t] : sy;
        sz = (js == t) ? qz[t] : sz;
      }
      cx = __int_as_float(__builtin_amdgcn_readlane(__float_as_int(sx), ls));
      cy = __int_as_float(__builtin_amdgcn_readlane(__float_as_int(sy), ls));
      cz = __int_as_float(__builtin_amdgcn_readlane(__float_as_int(sz), ls));
    }
  }
  __syncthreads();
  if (tid < 128) {
    int p = sel[tid];
    float4 v = pts[p];
    s2[b*128 + tid] = p;
    coorq2[((size_t)b*3 + 0)*128 + tid] = v.x;
    coorq2[((size_t)b*3 + 1)*128 + tid] = v.y;
    coorq2[((size_t)b*3 + 2)*128 + tid] = v.z;
    outc[((size_t)b*3 + 0)*128 + tid] = v.x;
    outc[((size_t)b*3 + 1)*128 + tid] = v.y;
    outc[((size_t)b*3 + 2)*128 + tid] = v.z;
  }
}

// ---------------------------------------------------------------------------
// mega1: blocks 0-7 FPS, 8-71 input_trans (block 8 zeroes stats), 72+ knn1.
// ---------------------------------------------------------------------------
__global__ __launch_bounds__(256) void mega1(
    const float* __restrict__ x, const float* __restrict__ w_in, const float* __restrict__ b_in,
    float* __restrict__ f0T, int* __restrict__ idx1,
    int* __restrict__ s1, float* __restrict__ coorq,
    int* __restrict__ s2, float* __restrict__ coorq2, float* __restrict__ outc,
    float* __restrict__ stats)
{
  __shared__ char smem_raw[35008] __attribute__((aligned(16)));
  const int bid = blockIdx.x;
  if (bid < 8) {
    fps_body(x, bid, s1, coorq, s2, coorq2, outc, smem_raw);
  } else if (bid < 72) {
    if (bid == 8) stats[threadIdx.x] = 0.f;   // consumed by mega2 (next dispatch)
    int t = (bid - 8)*256 + threadIdx.x;
    int b = t >> 11, n = t & 2047;
    float x0 = x[((size_t)b*3 + 0)*2048 + n];
    float x1 = x[((size_t)b*3 + 1)*2048 + n];
    float x2 = x[((size_t)b*3 + 2)*2048 + n];
    float* op = f0T + (size_t)t*8;
    #pragma unroll
    for (int o = 0; o < 8; ++o)
      op[o] = w_in[o*3+0]*x0 + w_in[o*3+1]*x1 + w_in[o*3+2]*x2 + b_in[o];
  } else {
    int vb = bid - 72;
    int b = vb >> 9;
    int qbase = (vb & 511)*4;
    knn_body<2048>(x, 2048, x, idx1, b, qbase, (float*)smem_raw);
  }
}

// ---------------------------------------------------------------------------
// Edge conv pass1 body (r2/r8 verbatim).
// ---------------------------------------------------------------------------
template<int C, int O, int NQ, int NK, bool STORE>
DI void conv_p1_body(
    const float* __restrict__ xqT, int xq_cols, const int* __restrict__ qg,
    const float* __restrict__ xkT, const int* __restrict__ knn_idx,
    const float* __restrict__ w, float* __restrict__ y, float* __restrict__ stats,
    int nt, int g, int b, float* smem)
{
  constexpr int GRP = O/4;
  const int tid = threadIdx.x;
  float* sxq = smem;
  float* sw  = smem + 16*C;
  float* red = sw + GRP*2*C;
  for (int i = tid; i < 16*C; i += 256) {
    int nn = i / C, ci = i % C;
    int q = nt*16 + nn;
    int src = qg ? qg[b*NQ + q] : q;
    sxq[i] = xqT[((size_t)b*xq_cols + src)*C + ci];
  }
  for (int i = tid; i < GRP*2*C; i += 256)
    sw[i] = w[(size_t)g*GRP*2*C + i];
  __syncthreads();

  const int nloc = tid >> 4, kk = tid & 15;
  const int n = nt*16 + nloc;
  const int flat = n*16 + kk;
  const int r = flat / NQ, s = flat % NQ;
  const int nbr = knn_idx[((size_t)b*16 + r)*NQ + s];

  float xqv[C], h1[C];
  {
    const float4* xq4 = (const float4*)(sxq + nloc*C);
    const float4* xk4 = (const float4*)(xkT + ((size_t)b*NK + nbr)*C);
    #pragma unroll
    for (int c4 = 0; c4 < C/4; ++c4) {
      float4 a = xq4[c4], k = xk4[c4];
      xqv[4*c4+0] = a.x; xqv[4*c4+1] = a.y; xqv[4*c4+2] = a.z; xqv[4*c4+3] = a.w;
      h1[4*c4+0] = k.x - a.x; h1[4*c4+1] = k.y - a.y;
      h1[4*c4+2] = k.z - a.z; h1[4*c4+3] = k.w - a.w;
    }
  }
  float lsum = 0.f, lsq = 0.f;
  float* yp = nullptr;
  if constexpr (STORE) yp = y + (((size_t)b*O + (size_t)g*GRP)*NQ + n)*16 + kk;
  for (int o = 0; o < GRP; ++o) {
    const float4* wr = (const float4*)(sw + o*2*C);
    float acc = 0.f;
    #pragma unroll
    for (int c4 = 0; c4 < C/4; ++c4) {
      float4 w4 = wr[c4];
      acc += w4.x*h1[4*c4] + w4.y*h1[4*c4+1] + w4.z*h1[4*c4+2] + w4.w*h1[4*c4+3];
    }
    #pragma unroll
    for (int c4 = 0; c4 < C/4; ++c4) {
      float4 w4 = wr[C/4 + c4];
      acc += w4.x*xqv[4*c4] + w4.y*xqv[4*c4+1] + w4.z*xqv[4*c4+2] + w4.w*xqv[4*c4+3];
    }
    if constexpr (STORE) yp[(size_t)o*NQ*16] = acc;
    lsum += acc; lsq += acc*acc;
  }
  #pragma unroll
  for (int off = 32; off; off >>= 1) {
    lsum += __shfl_xor(lsum, off);
    lsq  += __shfl_xor(lsq, off);
  }
  const int lane = tid & 63, wvid = tid >> 6;
  if (lane == 0) { red[wvid] = lsum; red[4+wvid] = lsq; }
  __syncthreads();
  if (tid == 0) {
    float s0  = (red[0]+red[1]) + (red[2]+red[3]);
    float s1v = (red[4]+red[5]) + (red[6]+red[7]);
    atomicAdd(stats + ((size_t)b*4 + g)*2,     s0);
    atomicAdd(stats + ((size_t)b*4 + g)*2 + 1, s1v);
  }
}

template<int C, int O, int NQ, int NK, bool STORE>
__global__ __launch_bounds__(256) void conv_p1(
    const float* __restrict__ xqT, int xq_cols, const int* __restrict__ qg,
    const float* __restrict__ xkT, const int* __restrict__ knn_idx,
    const float* __restrict__ w, float* __restrict__ y, float* __restrict__ stats)
{
  __shared__ float smem_f[16*C + (O/4)*2*C + 8];
  conv_p1_body<C, O, NQ, NK, STORE>(xqT, xq_cols, qg, xkT, knn_idx, w, y, stats,
                                    blockIdx.x, blockIdx.y, blockIdx.z, smem_f);
}

// ---------------------------------------------------------------------------
// mega2: knn2 + conv_p1(L1 stats) + knn3 + knn4 in one dispatch.
// ---------------------------------------------------------------------------
__global__ __launch_bounds__(256) void mega2(
    const float* __restrict__ f0T, const int* __restrict__ idx1,
    const float* __restrict__ w1, float* __restrict__ stats,
    const float* __restrict__ x, const float* __restrict__ coorq,
    const float* __restrict__ coorq2,
    int* __restrict__ idx2, int* __restrict__ idx3, int* __restrict__ idx4)
{
  __shared__ char smem_raw[32768] __attribute__((aligned(16)));
  const int bid = blockIdx.x;
  if (bid < 1024) {
    knn_body<2048>(coorq, 512, x, idx2, bid >> 7, (bid & 127)*4, (float*)smem_raw);
  } else if (bid < 5120) {
    int f = bid - 1024;
    conv_p1_body<8, 32, 2048, 2048, false>(f0T, 2048, nullptr, f0T, idx1, w1,
                                           nullptr, stats,
                                           f & 127, (f >> 7) & 3, f >> 9,
                                           (float*)smem_raw);
  } else if (bid < 6144) {
    int v = bid - 5120;
    knn_body<512>(coorq, 512, coorq, idx3, v >> 7, (v & 127)*4, (float*)smem_raw);
  } else {
    int v = bid - 6144;
    knn_body<512>(coorq2, 128, coorq, idx4, v >> 5, (v & 31)*4, (float*)smem_raw);
  }
}

// pass2 (r8 verbatim).
template<int O, int NQ, bool TOUT>
__global__ __launch_bounds__(256) void conv_p2(
    const float* __restrict__ y, const float* __restrict__ stats,
    const float* __restrict__ gamma, const float* __restrict__ beta,
    float* __restrict__ fout)
{
  int t = blockIdx.x*256 + threadIdx.x;
  if (t >= 8*O*NQ) return;
  int b = t / (O*NQ);
  int rem = t % (O*NQ);
  int o, n;
  if (TOUT) { o = rem % O; n = rem / O; }
  else      { n = rem % NQ; o = rem / NQ; }
  int g = o / (O/4);
  const float cnt = (float)((O/4) * NQ * 16);
  float s0 = stats[((size_t)b*4 + g)*2], s1v = stats[((size_t)b*4 + g)*2 + 1];
  float mu = s0 / cnt;
  float var = fmaxf(s1v / cnt - mu*mu, 0.f);
  float rs = 1.f / sqrtf(var + 1e-5f);
  float ga = gamma[o], be = beta[o];
  const float4* yp = (const float4*)(y + ((((size_t)b*O + o)*NQ) + n)*16);
  float m = -FLT_MAX;
  #pragma unroll
  for (int i = 0; i < 4; ++i) {
    float4 v4 = yp[i];
    float vv[4] = {v4.x, v4.y, v4.z, v4.w};
    #pragma unroll
    for (int j = 0; j < 4; ++j) {
      float a = (vv[j] - mu)*rs*ga + be;
      a = a >= 0.f ? a : 0.2f*a;
      m = fmaxf(m, a);
    }
  }
  fout[t] = m;
}

// Layer-1 pass2: recompute conv + GN + lrelu + max (r2/r8 verbatim).
__global__ __launch_bounds__(256) void l1_pass2(
    const float* __restrict__ f0T, const int* __restrict__ idx1,
    const float* __restrict__ w1, const float* __restrict__ stats,
    const float* __restrict__ g1, const float* __restrict__ be1,
    float* __restrict__ f1T)
{
  alignas(16) __shared__ float sw[512];
  __shared__ float sg[32], sb[32];
  int tid = threadIdx.x;
  for (int i = tid; i < 512; i += 256) sw[i] = w1[i];
  if (tid < 32) { sg[tid] = g1[tid]; sb[tid] = be1[tid]; }
  __syncthreads();
  int t = blockIdx.x*256 + tid;
  int b = t >> 11, n = t & 2047;
  float mean[4], rstd[4];
  const float cnt = 8.f*2048.f*16.f;
  #pragma unroll
  for (int g = 0; g < 4; ++g) {
    float mu = stats[(b*4+g)*2] / cnt;
    float var = fmaxf(stats[(b*4+g)*2+1]/cnt - mu*mu, 0.f);
    mean[g] = mu; rstd[g] = 1.f/sqrtf(var + 1e-5f);
  }
  const float4* xqp = (const float4*)(f0T + (size_t)t*8);
  float4 q0 = xqp[0], q1 = xqp[1];
  float xq[8] = {q0.x,q0.y,q0.z,q0.w,q1.x,q1.y,q1.z,q1.w};
  float h[16][8];
  #pragma unroll
  for (int kk = 0; kk < 16; ++kk) {
    int flat = n*16 + kk, r = flat >> 11, s = flat & 2047;
    int nbr = idx1[((b*16 + r) << 11) + s];
    const float4* xkp = (const float4*)(f0T + ((size_t)(b << 11) + nbr)*8);
    float4 k0 = xkp[0], k1 = xkp[1];
    h[kk][0]=k0.x-xq[0]; h[kk][1]=k0.y-xq[1]; h[kk][2]=k0.z-xq[2]; h[kk][3]=k0.w-xq[3];
    h[kk][4]=k1.x-xq[4]; h[kk][5]=k1.y-xq[5]; h[kk][6]=k1.z-xq[6]; h[kk][7]=k1.w-xq[7];
  }
  float* op = f1T + (size_t)t*32;
  for (int o = 0; o < 32; ++o) {
    const float4* wp4 = (const float4*)(sw + o*16);
    float4 wa = wp4[0], wb = wp4[1], wc = wp4[2], wd = wp4[3];
    float base = wc.x*xq[0]+wc.y*xq[1]+wc.z*xq[2]+wc.w*xq[3]
               + wd.x*xq[4]+wd.y*xq[5]+wd.z*xq[6]+wd.w*xq[7];
    int g = o >> 3;
    float mu = mean[g], rs = rstd[g], ga = sg[o], be = sb[o];
    float m = -FLT_MAX;
    #pragma unroll
    for (int kk = 0; kk < 16; ++kk) {
      float acc = base
        + wa.x*h[kk][0]+wa.y*h[kk][1]+wa.z*h[kk][2]+wa.w*h[kk][3]
        + wb.x*h[kk][4]+wb.y*h[kk][5]+wb.z*h[kk][6]+wb.w*h[kk][7];
      float a2 = (acc - mu)*rs*ga + be;
      a2 = a2 >= 0.f ? a2 : 0.2f*a2;
      m = fmaxf(m, a2);
    }
    op[o] = m;
  }
}

// ---------------------------------------------------------------------------
extern "C" void kernel_launch(void* const* d_in, const int* in_sizes, int n_in,
                              void* d_out, int out_size, void* d_ws, size_t ws_size,
                              hipStream_t stream)
{
  (void)in_sizes; (void)n_in; (void)out_size; (void)ws_size;
  const float* x    = (const float*)d_in[0];
  const float* w_in = (const float*)d_in[1];
  const float* b_in = (const float*)d_in[2];
  const float* w1   = (const float*)d_in[3];
  const float* g1   = (const float*)d_in[4];
  const float* be1  = (const float*)d_in[5];
  const float* w2   = (const float*)d_in[6];
  const float* g2   = (const float*)d_in[7];
  const float* be2  = (const float*)d_in[8];
  const float* w3   = (const float*)d_in[9];
  const float* g3   = (const float*)d_in[10];
  const float* be3  = (const float*)d_in[11];
  const float* w4   = (const float*)d_in[12];
  const float* g4   = (const float*)d_in[13];
  const float* be4  = (const float*)d_in[14];

  float* ws = (float*)d_ws;
  float* stats  = ws;                         // 256
  float* f0T    = ws + 256;                   // [8,2048,8]
  int*   idx1   = (int*)(ws + 131328);        // [8,16,2048]
  float* f1T    = ws + 393472;                // [8,2048,32]
  int*   s1     = (int*)(ws + 917760);        // [8,512]
  float* coorq  = ws + 921856;                // [8,3,512]
  int*   idx2   = (int*)(ws + 934144);        // [8,16,512]
  float* f2T    = ws + 999680;                // [8,512,64]
  int*   idx3   = (int*)(ws + 1261824);       // [8,16,512]
  float* f3T    = ws + 1327360;               // [8,512,64]
  int*   s2     = (int*)(ws + 1589504);       // [8,128]
  float* coorq2 = ws + 1590528;               // [8,3,128]
  int*   idx4   = (int*)(ws + 1593600);       // [8,16,128]
  float* ybuf   = ws + 1609984;               // up to [8,64,512,16]

  float* outc = (float*)d_out;                // [8,3,128]
  float* f4   = (float*)d_out + 3072;         // [8,128,128]

  // FPS(1+2) + input_trans (+ stats zeroing) + knn1.
  mega1<<<dim3(4168), 256, 0, stream>>>(
      x, w_in, b_in, f0T, idx1, s1, coorq, s2, coorq2, outc, stats);

  // knn2 + L1 stats + knn3 + knn4.
  mega2<<<dim3(6400), 256, 0, stream>>>(
      f0T, idx1, w1, stats, x, coorq, coorq2, idx2, idx3, idx4);

  // Layer 1 finish.
  l1_pass2<<<64, 256, 0, stream>>>(f0T, idx1, w1, stats, g1, be1, f1T);

  // Layer 2 (C=32 -> O=64, Nq=512, Nk=2048), x_q gathered by s1.
  conv_p1<32, 64, 512, 2048, true><<<dim3(32, 4, 8), 256, 0, stream>>>(
      f1T, 2048, s1, f1T, idx2, w2, ybuf, stats + 64);
  conv_p2<64, 512, true><<<1024, 256, 0, stream>>>(ybuf, stats + 64, g2, be2, f2T);

  // Layer 3 (C=64 -> O=64, Nq=Nk=512).
  conv_p1<64, 64, 512, 512, true><<<dim3(32, 4, 8), 256, 0, stream>>>(
      f2T, 512, nullptr, f2T, idx3, w3, ybuf, stats + 128);
  conv_p2<64, 512, true><<<1024, 256, 0, stream>>>(ybuf, stats + 128, g3, be3, f3T);

  // Layer 4 (C=64 -> O=128, Nq=128, Nk=512), x_q gathered by s2.
  conv_p1<64, 128, 128, 512, true><<<dim3(8, 4, 8), 256, 0, stream>>>(
      f3T, 512, s2, f3T, idx4, w4, ybuf, stats + 192);
  conv_p2<128, 128, false><<<512, 256, 0, stream>>>(ybuf, stats + 192, g4, be4, f4);
}

// Round 12
// 446.350 us; speedup vs baseline: 2.0969x; 2.0969x over previous
//
#include <hip/hip_runtime.h>
#include <float.h>
#include <stdint.h>

// DGCNN_Grouper forward on MI355X. B=8, N=2048, K=16, fp32.
// r8 architecture + r11 change: knn1/in_trans/L1-conv/GN-stats/k-minmax fused
// into one block type (scrambled gather is block-local for 16-query blocks),
// all hidden under FPS in mega1. l1_pass2 becomes elementwise select.
// FPS = r8-verbatim 4-wave (273us, best measured). Stream-ordered only.

#define DI __device__ __forceinline__
DI float f_add(float a, float b) { return __fadd_rn(a, b); }
DI float f_sub(float a, float b) { return __fsub_rn(a, b); }
DI float f_mul(float a, float b) { return __fmul_rn(a, b); }

DI uint64_t umax64(uint64_t a, uint64_t b) { return a > b ? a : b; }

// ---------------------------------------------------------------------------
// 32-bit DPP wave reduces (6-step gfx9 pattern; validated r8).
// ---------------------------------------------------------------------------
template<int CTRL, int RMASK>
DI uint32_t dpp_umax32(uint32_t v) {
  uint32_t o = (uint32_t)__builtin_amdgcn_update_dpp(0, (int)v, CTRL, RMASK, 0xF, false);
  return v > o ? v : o;
}
template<int CTRL, int RMASK>
DI uint32_t dpp_umin32(uint32_t v) {
  uint32_t o = (uint32_t)__builtin_amdgcn_update_dpp(-1, (int)v, CTRL, RMASK, 0xF, false);
  return v < o ? v : o;
}
template<int CTRL, int RMASK>
DI float dpp_fmin32(float v) {
  int o = __builtin_amdgcn_update_dpp(0x7F7FFFFF /*FLT_MAX*/, __float_as_int(v),
                                      CTRL, RMASK, 0xF, false);
  return fminf(v, __int_as_float(o));
}
DI uint32_t wave_umax_bcast32(uint32_t v) {
  v = dpp_umax32<0x111, 0xF>(v);
  v = dpp_umax32<0x112, 0xF>(v);
  v = dpp_umax32<0x114, 0xF>(v);
  v = dpp_umax32<0x118, 0xF>(v);
  v = dpp_umax32<0x142, 0xA>(v);
  v = dpp_umax32<0x143, 0xC>(v);
  return (uint32_t)__builtin_amdgcn_readlane((int)v, 63);
}
DI uint32_t wave_umin_bcast32(uint32_t v) {
  v = dpp_umin32<0x111, 0xF>(v);
  v = dpp_umin32<0x112, 0xF>(v);
  v = dpp_umin32<0x114, 0xF>(v);
  v = dpp_umin32<0x118, 0xF>(v);
  v = dpp_umin32<0x142, 0xA>(v);
  v = dpp_umin32<0x143, 0xC>(v);
  return (uint32_t)__builtin_amdgcn_readlane((int)v, 63);
}
DI float wave_fmin_bcast32(float v) {
  v = dpp_fmin32<0x111, 0xF>(v);
  v = dpp_fmin32<0x112, 0xF>(v);
  v = dpp_fmin32<0x114, 0xF>(v);
  v = dpp_fmin32<0x118, 0xF>(v);
  v = dpp_fmin32<0x142, 0xA>(v);
  v = dpp_fmin32<0x143, 0xC>(v);
  return __int_as_float(__builtin_amdgcn_readlane(__float_as_int(v), 63));
}

// ---------------------------------------------------------------------------
// kNN (r8 verbatim): 16 smallest d2; f32-min phase + u32-min index phase.
// ---------------------------------------------------------------------------
template<int NK>
DI void knn_body(const float* __restrict__ cq, int Nq,
                 const float* __restrict__ ck, int* __restrict__ out,
                 int b, int qbase, float* smem)
{
  constexpr int CPL = NK / 64;
  float* xs = smem;
  float* ys = smem + NK;
  float* zs = smem + 2*NK;
  float* rr = smem + 3*NK;
  const int tid = threadIdx.x;
  for (int i = tid; i < NK; i += 256) {
    float a  = ck[((size_t)b*3 + 0)*NK + i];
    float bb = ck[((size_t)b*3 + 1)*NK + i];
    float c  = ck[((size_t)b*3 + 2)*NK + i];
    xs[i] = a; ys[i] = bb; zs[i] = c;
    rr[i] = f_add(f_add(f_mul(a,a), f_mul(bb,bb)), f_mul(c,c));
  }
  __syncthreads();
  const int lane = tid & 63, w = tid >> 6;
  const int q = qbase + w;
  if (q >= Nq) return;
  float qx = cq[((size_t)b*3 + 0)*Nq + q];
  float qy = cq[((size_t)b*3 + 1)*Nq + q];
  float qz = cq[((size_t)b*3 + 2)*Nq + q];
  float qq = f_add(f_add(f_mul(qx,qx), f_mul(qy,qy)), f_mul(qz,qz));
  float v[CPL];
  #pragma unroll
  for (int j = 0; j < CPL; ++j) {
    int c = j*64 + lane;
    float dot = f_add(f_add(f_mul(qx,xs[c]), f_mul(qy,ys[c])), f_mul(qz,zs[c]));
    v[j] = f_sub(f_add(qq, rr[c]), f_mul(2.0f, dot));
  }
  unsigned mask = (CPL >= 32) ? 0xFFFFFFFFu : ((1u << CPL) - 1u);
  for (int r = 0; r < 16; ++r) {
    float bv = FLT_MAX; int bc = 0x7FFFFFFF;
    #pragma unroll
    for (int j = 0; j < CPL; ++j) {
      float vj = ((mask >> j) & 1u) ? v[j] : FLT_MAX;
      if (vj < bv) { bv = vj; bc = j*64 + lane; }
    }
    float wmin = wave_fmin_bcast32(bv);
    uint32_t cand = (bv == wmin) ? (uint32_t)bc : 0xFFFFFFFFu;
    uint32_t wbc = wave_umin_bcast32(cand);
    if ((wbc & 63) == (uint32_t)lane) mask &= ~(1u << (wbc >> 6));
    if (lane == 0) out[((size_t)b*16 + r)*Nq + q] = (int)wbc;
  }
}

// ---------------------------------------------------------------------------
// FPS (r8 VERBATIM — 4-wave level1, two-phase u32 reduce; 273us measured).
// ---------------------------------------------------------------------------
__device__ void fps_body(const float* __restrict__ x, int b,
                         int* __restrict__ s1, float* __restrict__ coorq,
                         int* __restrict__ s2, float* __restrict__ coorq2,
                         float* __restrict__ outc, char* smem_raw)
{
  float4*   pts  = (float4*)smem_raw;                       // [2048]
  int*      sel  = (int*)(smem_raw + 32768);                // [512]
  uint64_t* wkey = (uint64_t*)(smem_raw + 32768 + 2048);    // [8]
  const int tid = threadIdx.x, lane = tid & 63, w = tid >> 6;

  for (int i = tid; i < 2048; i += 256)
    pts[i] = make_float4(x[((size_t)b*3 + 0)*2048 + i],
                         x[((size_t)b*3 + 1)*2048 + i],
                         x[((size_t)b*3 + 2)*2048 + i], 0.f);
  __syncthreads();

  float px[8], py[8], pz[8], dl[8];
  #pragma unroll
  for (int j = 0; j < 8; ++j) {
    float4 p = pts[tid + 256*j];
    px[j] = p.x; py[j] = p.y; pz[j] = p.z; dl[j] = 1e10f;
  }

  int far = 0;
  float4 c = pts[0];
  for (int i = 0; i < 512; ++i) {
    if (tid == 0) sel[i] = far;
    float bd = -1.0f; uint32_t bi = 0;
    #pragma unroll
    for (int j = 0; j < 8; ++j) {
      float dx = f_sub(px[j], c.x);
      float dy = f_sub(py[j], c.y);
      float dz = f_sub(pz[j], c.z);
      float d  = f_add(f_add(f_mul(dx,dx), f_mul(dy,dy)), f_mul(dz,dz));
      float nd = fminf(dl[j], d);
      dl[j] = nd;
      if (nd > bd) { bd = nd; bi = (uint32_t)(tid + 256*j); }
    }
    uint32_t db = __float_as_uint(bd);
    uint32_t wd = wave_umax_bcast32(db);
    uint32_t cand = (db == wd) ? bi : 0xFFFFFFFFu;
    uint32_t wi = wave_umin_bcast32(cand);
    if (lane == 0) wkey[(i & 1)*4 + w] = ((uint64_t)wd << 32) | (uint32_t)~wi;
    __syncthreads();
    const uint64_t* wk = wkey + (i & 1)*4;
    uint64_t g = umax64(umax64(wk[0], wk[1]), umax64(wk[2], wk[3]));
    far = (int)~(uint32_t)g;
    c = pts[far];
  }
  __syncthreads();

  int p0 = sel[tid], p1 = sel[tid + 256];
  float4 v0 = pts[p0], v1 = pts[p1];
  s1[b*512 + tid]       = p0;
  s1[b*512 + tid + 256] = p1;
  coorq[((size_t)b*3 + 0)*512 + tid] = v0.x;
  coorq[((size_t)b*3 + 1)*512 + tid] = v0.y;
  coorq[((size_t)b*3 + 2)*512 + tid] = v0.z;
  coorq[((size_t)b*3 + 0)*512 + tid + 256] = v1.x;
  coorq[((size_t)b*3 + 1)*512 + tid + 256] = v1.y;
  coorq[((size_t)b*3 + 2)*512 + tid + 256] = v1.z;
  __syncthreads();
  pts[tid] = v0; pts[tid + 256] = v1;
  __syncthreads();

  if (w == 0) {
    float qx[8], qy[8], qz[8], d2[8];
    #pragma unroll
    for (int j = 0; j < 8; ++j) {
      float4 p = pts[lane + 64*j];
      qx[j] = p.x; qy[j] = p.y; qz[j] = p.z; d2[j] = 1e10f;
    }
    int far2 = 0;
    float cx = pts[0].x, cy = pts[0].y, cz = pts[0].z;
    for (int i = 0; i < 128; ++i) {
      if (lane == 0) sel[i] = far2;
      float bd = -1.0f; uint32_t bi = 0;
      #pragma unroll
      for (int j = 0; j < 8; ++j) {
        float dx = f_sub(qx[j], cx);
        float dy = f_sub(qy[j], cy);
        float dz = f_sub(qz[j], cz);
        float d  = f_add(f_add(f_mul(dx,dx), f_mul(dy,dy)), f_mul(dz,dz));
        float nd = fminf(d2[j], d);
        d2[j] = nd;
        if (nd > bd) { bd = nd; bi = (uint32_t)(lane + 64*j); }
      }
      uint32_t db = __float_as_uint(bd);
      uint32_t wd = wave_umax_bcast32(db);
      uint32_t cand = (db == wd) ? bi : 0xFFFFFFFFu;
      uint32_t wi = wave_umin_bcast32(cand);
      far2 = (int)wi;
      uint32_t js = wi >> 6, ls = wi & 63;
      float sx = qx[0], sy = qy[0], sz = qz[0];
      #pragma unroll
      for (uint32_t t = 1; t < 8; ++t) {
        sx = (js == t) ? qx[t] : sx;
        sy = (js == t) ? qy[t] : sy;
        sz = (js == t) ? qz[t] : sz;
      }
      cx = __int_as_float(__builtin_amdgcn_readlane(__float_as_int(sx), ls));
      cy = __int_as_float(__builtin_amdgcn_readlane(__float_as_int(sy), ls));
      cz = __int_as_float(__builtin_amdgcn_readlane(__float_as_int(sz), ls));
    }
  }
  __syncthreads();
  if (tid < 128) {
    int p = sel[tid];
    float4 v = pts[p];
    s2[b*128 + tid] = p;
    coorq2[((size_t)b*3 + 0)*128 + tid] = v.x;
    coorq2[((size_t)b*3 + 1)*128 + tid] = v.y;
    coorq2[((size_t)b*3 + 2)*128 + tid] = v.z;
    outc[((size_t)b*3 + 0)*128 + tid] = v.x;
    outc[((size_t)b*3 + 1)*128 + tid] = v.y;
    outc[((size_t)b*3 + 2)*128 + tid] = v.z;
  }
}

// ---------------------------------------------------------------------------
// Fused L1 block: 16 queries (S..S+15) of batch b.
// knn1 (exact r8 algorithm, coords from LDS) -> idxloc[qi][r]; then conv1 for
// outputs n = r*128 + (S>>4) using ONLY local idx entries (scrambled gather:
// feat[n,k] = f0[idx1[n>>7][(n&127)*16+k]], block-local for these n).
// Produces ymax/ymin per (n,o) + GN stats. f0 computed on the fly from coords.
// ---------------------------------------------------------------------------
__device__ void fused_l1_body(const float* __restrict__ x,
                              const float* __restrict__ w_in, const float* __restrict__ b_in,
                              const float* __restrict__ w1,
                              float* __restrict__ ymax1, float* __restrict__ ymin1,
                              float* __restrict__ stats,
                              int b, int S, char* smem_raw)
{
  float* xs = (float*)smem_raw;                 // 2048
  float* ys = xs + 2048;
  float* zs = xs + 4096;
  float* rr = xs + 6144;
  int*   idxloc = (int*)(xs + 8192);            // [16 qi][16 r]
  float* sw1  = (float*)(idxloc + 256);         // 512 (w1)
  float* winb = sw1 + 512;                      // 24 w_in + 8 b_in
  float* red  = winb + 32;                      // 32 (4 waves x 8)
  const int tid = threadIdx.x, lane = tid & 63, w = tid >> 6;

  for (int i = tid; i < 2048; i += 256) {
    float a  = x[((size_t)b*3 + 0)*2048 + i];
    float bb = x[((size_t)b*3 + 1)*2048 + i];
    float c  = x[((size_t)b*3 + 2)*2048 + i];
    xs[i] = a; ys[i] = bb; zs[i] = c;
    rr[i] = f_add(f_add(f_mul(a,a), f_mul(bb,bb)), f_mul(c,c));
  }
  for (int i = tid; i < 512; i += 256) sw1[i] = w1[i];
  if (tid < 24) winb[tid] = w_in[tid];
  if (tid < 8)  winb[24 + tid] = b_in[tid];
  __syncthreads();

  // knn phase: wave w handles queries qi = 4w..4w+3 (sequential).
  for (int qq = 0; qq < 4; ++qq) {
    int qi = w*4 + qq;
    int q = S + qi;
    float qx = xs[q], qy = ys[q], qz = zs[q];
    float qqv = f_add(f_add(f_mul(qx,qx), f_mul(qy,qy)), f_mul(qz,qz));
    float v[32];
    #pragma unroll
    for (int j = 0; j < 32; ++j) {
      int c = j*64 + lane;
      float dot = f_add(f_add(f_mul(qx,xs[c]), f_mul(qy,ys[c])), f_mul(qz,zs[c]));
      v[j] = f_sub(f_add(qqv, rr[c]), f_mul(2.0f, dot));
    }
    unsigned mask = 0xFFFFFFFFu;
    for (int r = 0; r < 16; ++r) {
      float bv = FLT_MAX; int bc = 0x7FFFFFFF;
      #pragma unroll
      for (int j = 0; j < 32; ++j) {
        float vj = ((mask >> j) & 1u) ? v[j] : FLT_MAX;
        if (vj < bv) { bv = vj; bc = j*64 + lane; }
      }
      float wmin = wave_fmin_bcast32(bv);
      uint32_t cand = (bv == wmin) ? (uint32_t)bc : 0xFFFFFFFFu;
      uint32_t wbc = wave_umin_bcast32(cand);
      if ((wbc & 63) == (uint32_t)lane) mask &= ~(1u << (wbc >> 6));
      if (lane == 0) idxloc[qi*16 + r] = (int)wbc;
    }
  }
  __syncthreads();

  // conv phase: thread (r = tid>>4, k = tid&15). Output n = r*128 + (S>>4);
  // feat[n,k] = f0[idxloc[k][r]] (query S+k's r-th NN).
  const int r = tid >> 4, k = tid & 15;
  const int nbr = idxloc[k*16 + r];
  const int ng  = r*128 + (S >> 4);
  float f0n[8], f0q[8], h[8];
  #pragma unroll
  for (int o = 0; o < 8; ++o) {
    f0n[o] = winb[o*3+0]*xs[nbr] + winb[o*3+1]*ys[nbr] + winb[o*3+2]*zs[nbr] + winb[24+o];
    f0q[o] = winb[o*3+0]*xs[ng]  + winb[o*3+1]*ys[ng]  + winb[o*3+2]*zs[ng]  + winb[24+o];
    h[o] = f0n[o] - f0q[o];
  }
  float gsum[4] = {0.f,0.f,0.f,0.f}, gsq[4] = {0.f,0.f,0.f,0.f};
  float* ymx = ymax1 + ((size_t)b*2048 + ng)*32;
  float* ymn = ymin1 + ((size_t)b*2048 + ng)*32;
  for (int o = 0; o < 32; ++o) {
    const float4* wr = (const float4*)(sw1 + o*16);
    float4 wa = wr[0], wb4 = wr[1], wc = wr[2], wd = wr[3];
    float acc = wa.x*h[0]+wa.y*h[1]+wa.z*h[2]+wa.w*h[3]
              + wb4.x*h[4]+wb4.y*h[5]+wb4.z*h[6]+wb4.w*h[7]
              + wc.x*f0q[0]+wc.y*f0q[1]+wc.z*f0q[2]+wc.w*f0q[3]
              + wd.x*f0q[4]+wd.y*f0q[5]+wd.z*f0q[6]+wd.w*f0q[7];
    float mx = acc, mn = acc;
    #pragma unroll
    for (int off = 1; off < 16; off <<= 1) {
      mx = fmaxf(mx, __shfl_xor(mx, off));
      mn = fminf(mn, __shfl_xor(mn, off));
    }
    if (k == 0) { ymx[o] = mx; ymn[o] = mn; }
    int g = o >> 3;
    gsum[g] += acc; gsq[g] += acc*acc;
  }
  #pragma unroll
  for (int g = 0; g < 4; ++g) {
    #pragma unroll
    for (int off = 1; off < 64; off <<= 1) {
      gsum[g] += __shfl_xor(gsum[g], off);
      gsq[g]  += __shfl_xor(gsq[g], off);
    }
  }
  if (lane == 0) {
    #pragma unroll
    for (int g = 0; g < 4; ++g) { red[w*8 + g] = gsum[g]; red[w*8 + 4 + g] = gsq[g]; }
  }
  __syncthreads();
  if (tid == 0) {
    #pragma unroll
    for (int g = 0; g < 4; ++g) {
      float s0  = (red[g] + red[8+g]) + (red[16+g] + red[24+g]);
      float s1v = (red[4+g] + red[12+g]) + (red[20+g] + red[28+g]);
      atomicAdd(stats + (b*4 + g)*2,     s0);
      atomicAdd(stats + (b*4 + g)*2 + 1, s1v);
    }
  }
}

// ---------------------------------------------------------------------------
// mega1: blocks 0-7 FPS; blocks 8..1031 fused L1 (128 blocks/batch).
// ---------------------------------------------------------------------------
__global__ __launch_bounds__(256) void mega1(
    const float* __restrict__ x, const float* __restrict__ w_in, const float* __restrict__ b_in,
    const float* __restrict__ w1,
    float* __restrict__ ymax1, float* __restrict__ ymin1, float* __restrict__ stats,
    int* __restrict__ s1, float* __restrict__ coorq,
    int* __restrict__ s2, float* __restrict__ coorq2, float* __restrict__ outc)
{
  __shared__ char smem_raw[36352] __attribute__((aligned(16)));
  const int bid = blockIdx.x;
  if (bid < 8) {
    fps_body(x, bid, s1, coorq, s2, coorq2, outc, smem_raw);
  } else {
    int vb = bid - 8;
    fused_l1_body(x, w_in, b_in, w1, ymax1, ymin1, stats,
                  vb >> 7, (vb & 127)*16, smem_raw);
  }
}

// ---------------------------------------------------------------------------
// mega2: l1 finish (elementwise GN+lrelu via ymax/ymin select) + knn2/3/4.
// ---------------------------------------------------------------------------
__global__ __launch_bounds__(256) void mega2(
    const float* __restrict__ ymax1, const float* __restrict__ ymin1,
    const float* __restrict__ stats,
    const float* __restrict__ g1, const float* __restrict__ be1,
    float* __restrict__ f1T,
    const float* __restrict__ x, const float* __restrict__ coorq,
    const float* __restrict__ coorq2,
    int* __restrict__ idx2, int* __restrict__ idx3, int* __restrict__ idx4)
{
  __shared__ char smem_raw[32768] __attribute__((aligned(16)));
  const int bid = blockIdx.x;
  if (bid < 2048) {            // l1 finish: 524288 elems [(b*2048+n)*32+o]
    int t = bid*256 + threadIdx.x;
    int b = t >> 16;
    int o = t & 31;
    int g = o >> 3;
    const float cnt = 8.f*2048.f*16.f;
    float mu = stats[(b*4+g)*2] / cnt;
    float var = fmaxf(stats[(b*4+g)*2+1]/cnt - mu*mu, 0.f);
    float rs = 1.f/sqrtf(var + 1e-5f);
    float ga = g1[o], be = be1[o];
    float sel = (ga >= 0.f) ? ymax1[t] : ymin1[t];   // affine slope sign = sign(ga)
    float a = (sel - mu)*rs*ga + be;
    f1T[t] = a >= 0.f ? a : 0.2f*a;
  } else if (bid < 3072) {     // knn2
    int v = bid - 2048;
    knn_body<2048>(coorq, 512, x, idx2, v >> 7, (v & 127)*4, (float*)smem_raw);
  } else if (bid < 4096) {     // knn3
    int v = bid - 3072;
    knn_body<512>(coorq, 512, coorq, idx3, v >> 7, (v & 127)*4, (float*)smem_raw);
  } else {                     // knn4
    int v = bid - 4096;
    knn_body<512>(coorq2, 128, coorq, idx4, v >> 5, (v & 31)*4, (float*)smem_raw);
  }
}

// ---------------------------------------------------------------------------
// Edge conv pass1 (r8 verbatim).
// ---------------------------------------------------------------------------
template<int C, int O, int NQ, int NK, bool STORE>
DI void conv_p1_body(
    const float* __restrict__ xqT, int xq_cols, const int* __restrict__ qg,
    const float* __restrict__ xkT, const int* __restrict__ knn_idx,
    const float* __restrict__ w, float* __restrict__ y, float* __restrict__ stats,
    int nt, int g, int b, float* smem)
{
  constexpr int GRP = O/4;
  const int tid = threadIdx.x;
  float* sxq = smem;
  float* sw  = smem + 16*C;
  float* red = sw + GRP*2*C;
  for (int i = tid; i < 16*C; i += 256) {
    int nn = i / C, ci = i % C;
    int q = nt*16 + nn;
    int src = qg ? qg[b*NQ + q] : q;
    sxq[i] = xqT[((size_t)b*xq_cols + src)*C + ci];
  }
  for (int i = tid; i < GRP*2*C; i += 256)
    sw[i] = w[(size_t)g*GRP*2*C + i];
  __syncthreads();

  const int nloc = tid >> 4, kk = tid & 15;
  const int n = nt*16 + nloc;
  const int flat = n*16 + kk;
  const int r = flat / NQ, s = flat % NQ;
  const int nbr = knn_idx[((size_t)b*16 + r)*NQ + s];

  float xqv[C], h1[C];
  {
    const float4* xq4 = (const float4*)(sxq + nloc*C);
    const float4* xk4 = (const float4*)(xkT + ((size_t)b*NK + nbr)*C);
    #pragma unroll
    for (int c4 = 0; c4 < C/4; ++c4) {
      float4 a = xq4[c4], k = xk4[c4];
      xqv[4*c4+0] = a.x; xqv[4*c4+1] = a.y; xqv[4*c4+2] = a.z; xqv[4*c4+3] = a.w;
      h1[4*c4+0] = k.x - a.x; h1[4*c4+1] = k.y - a.y;
      h1[4*c4+2] = k.z - a.z; h1[4*c4+3] = k.w - a.w;
    }
  }
  float lsum = 0.f, lsq = 0.f;
  float* yp = nullptr;
  if constexpr (STORE) yp = y + (((size_t)b*O + (size_t)g*GRP)*NQ + n)*16 + kk;
  for (int o = 0; o < GRP; ++o) {
    const float4* wr = (const float4*)(sw + o*2*C);
    float acc = 0.f;
    #pragma unroll
    for (int c4 = 0; c4 < C/4; ++c4) {
      float4 w4 = wr[c4];
      acc += w4.x*h1[4*c4] + w4.y*h1[4*c4+1] + w4.z*h1[4*c4+2] + w4.w*h1[4*c4+3];
    }
    #pragma unroll
    for (int c4 = 0; c4 < C/4; ++c4) {
      float4 w4 = wr[C/4 + c4];
      acc += w4.x*xqv[4*c4] + w4.y*xqv[4*c4+1] + w4.z*xqv[4*c4+2] + w4.w*xqv[4*c4+3];
    }
    if constexpr (STORE) yp[(size_t)o*NQ*16] = acc;
    lsum += acc; lsq += acc*acc;
  }
  #pragma unroll
  for (int off = 32; off; off >>= 1) {
    lsum += __shfl_xor(lsum, off);
    lsq  += __shfl_xor(lsq, off);
  }
  const int lane = tid & 63, wvid = tid >> 6;
  if (lane == 0) { red[wvid] = lsum; red[4+wvid] = lsq; }
  __syncthreads();
  if (tid == 0) {
    float s0  = (red[0]+red[1]) + (red[2]+red[3]);
    float s1v = (red[4]+red[5]) + (red[6]+red[7]);
    atomicAdd(stats + ((size_t)b*4 + g)*2,     s0);
    atomicAdd(stats + ((size_t)b*4 + g)*2 + 1, s1v);
  }
}

template<int C, int O, int NQ, int NK, bool STORE>
__global__ __launch_bounds__(256) void conv_p1(
    const float* __restrict__ xqT, int xq_cols, const int* __restrict__ qg,
    const float* __restrict__ xkT, const int* __restrict__ knn_idx,
    const float* __restrict__ w, float* __restrict__ y, float* __restrict__ stats)
{
  __shared__ float smem_f[16*C + (O/4)*2*C + 8];
  conv_p1_body<C, O, NQ, NK, STORE>(xqT, xq_cols, qg, xkT, knn_idx, w, y, stats,
                                    blockIdx.x, blockIdx.y, blockIdx.z, smem_f);
}

// pass2 (r8 verbatim).
template<int O, int NQ, bool TOUT>
__global__ __launch_bounds__(256) void conv_p2(
    const float* __restrict__ y, const float* __restrict__ stats,
    const float* __restrict__ gamma, const float* __restrict__ beta,
    float* __restrict__ fout)
{
  int t = blockIdx.x*256 + threadIdx.x;
  if (t >= 8*O*NQ) return;
  int b = t / (O*NQ);
  int rem = t % (O*NQ);
  int o, n;
  if (TOUT) { o = rem % O; n = rem / O; }
  else      { n = rem % NQ; o = rem / NQ; }
  int g = o / (O/4);
  const float cnt = (float)((O/4) * NQ * 16);
  float s0 = stats[((size_t)b*4 + g)*2], s1v = stats[((size_t)b*4 + g)*2 + 1];
  float mu = s0 / cnt;
  float var = fmaxf(s1v / cnt - mu*mu, 0.f);
  float rs = 1.f / sqrtf(var + 1e-5f);
  float ga = gamma[o], be = beta[o];
  const float4* yp = (const float4*)(y + ((((size_t)b*O + o)*NQ) + n)*16);
  float m = -FLT_MAX;
  #pragma unroll
  for (int i = 0; i < 4; ++i) {
    float4 v4 = yp[i];
    float vv[4] = {v4.x, v4.y, v4.z, v4.w};
    #pragma unroll
    for (int j = 0; j < 4; ++j) {
      float a = (vv[j] - mu)*rs*ga + be;
      a = a >= 0.f ? a : 0.2f*a;
      m = fmaxf(m, a);
    }
  }
  fout[t] = m;
}

// ---------------------------------------------------------------------------
extern "C" void kernel_launch(void* const* d_in, const int* in_sizes, int n_in,
                              void* d_out, int out_size, void* d_ws, size_t ws_size,
                              hipStream_t stream)
{
  (void)in_sizes; (void)n_in; (void)out_size; (void)ws_size;
  const float* x    = (const float*)d_in[0];
  const float* w_in = (const float*)d_in[1];
  const float* b_in = (const float*)d_in[2];
  const float* w1   = (const float*)d_in[3];
  const float* g1   = (const float*)d_in[4];
  const float* be1  = (const float*)d_in[5];
  const float* w2   = (const float*)d_in[6];
  const float* g2   = (const float*)d_in[7];
  const float* be2  = (const float*)d_in[8];
  const float* w3   = (const float*)d_in[9];
  const float* g3   = (const float*)d_in[10];
  const float* be3  = (const float*)d_in[11];
  const float* w4   = (const float*)d_in[12];
  const float* g4   = (const float*)d_in[13];
  const float* be4  = (const float*)d_in[14];

  float* ws = (float*)d_ws;
  float* stats  = ws;                      // 256
  float* f1T    = ws + 256;                // [8,2048,32] -> 524544
  int*   s1     = (int*)(ws + 524544);     // [8,512]     -> 528640
  float* coorq  = ws + 528640;             // [8,3,512]   -> 540928
  int*   idx2   = (int*)(ws + 540928);     // [8,16,512]  -> 606464
  float* f2T    = ws + 606464;             // [8,512,64]  -> 868608
  int*   idx3   = (int*)(ws + 868608);     // [8,16,512]  -> 934144
  float* f3T    = ws + 934144;             // [8,512,64]  -> 1196288
  int*   s2     = (int*)(ws + 1196288);    // [8,128]     -> 1197312
  float* coorq2 = ws + 1197312;            // [8,3,128]   -> 1200384
  int*   idx4   = (int*)(ws + 1200384);    // [8,16,128]  -> 1216768
  float* ybuf   = ws + 1216768;            // [8,64,512,16] = 4194304
  // ymax1/ymin1 alias ybuf: dead before L2p1 (ybuf's first write).
  float* ymax1  = ybuf;                    // [8,2048,32]
  float* ymin1  = ybuf + 524288;           // [8,2048,32]

  float* outc = (float*)d_out;             // [8,3,128]
  float* f4   = (float*)d_out + 3072;      // [8,128,128]

  hipMemsetAsync(stats, 0, 256*sizeof(float), stream);

  // FPS + fused{knn1 + in_trans + L1 conv + stats + k-minmax}.
  mega1<<<dim3(1032), 256, 0, stream>>>(
      x, w_in, b_in, w1, ymax1, ymin1, stats, s1, coorq, s2, coorq2, outc);

  // L1 finish (elementwise) + knn2 + knn3 + knn4.
  mega2<<<dim3(4352), 256, 0, stream>>>(
      ymax1, ymin1, stats, g1, be1, f1T, x, coorq, coorq2, idx2, idx3, idx4);

  // Layer 2 (C=32 -> O=64, Nq=512, Nk=2048), x_q gathered by s1.
  conv_p1<32, 64, 512, 2048, true><<<dim3(32, 4, 8), 256, 0, stream>>>(
      f1T, 2048, s1, f1T, idx2, w2, ybuf, stats + 64);
  conv_p2<64, 512, true><<<1024, 256, 0, stream>>>(ybuf, stats + 64, g2, be2, f2T);

  // Layer 3 (C=64 -> O=64, Nq=Nk=512).
  conv_p1<64, 64, 512, 512, true><<<dim3(32, 4, 8), 256, 0, stream>>>(
      f2T, 512, nullptr, f2T, idx3, w3, ybuf, stats + 128);
  conv_p2<64, 512, true><<<1024, 256, 0, stream>>>(ybuf, stats + 128, g3, be3, f3T);

  // Layer 4 (C=64 -> O=128, Nq=128, Nk=512), x_q gathered by s2.
  conv_p1<64, 128, 128, 512, true><<<dim3(8, 4, 8), 256, 0, stream>>>(
      f3T, 512, s2, f3T, idx4, w4, ybuf, stats + 192);
  conv_p2<128, 128, false><<<512, 256, 0, stream>>>(ybuf, stats + 192, g4, be4, f4);
}

// Round 13
// 430.753 us; speedup vs baseline: 2.1729x; 1.0362x over previous
//
#include <hip/hip_runtime.h>
#include <float.h>
#include <stdint.h>

// DGCNN_Grouper forward on MI355X. B=8, N=2048, K=16, fp32.
// r12 architecture + r13 change: minmax trick extended to L2..L4 —
// conv_p1mm stores per-(n,o) ymax/ymin only; consumers dequantize the
// previous layer's features on the fly (exact GN+lrelu op order).
// 6 dispatches. FPS = r8-verbatim 4-wave. Stream-ordered only.

#define DI __device__ __forceinline__
DI float f_add(float a, float b) { return __fadd_rn(a, b); }
DI float f_sub(float a, float b) { return __fsub_rn(a, b); }
DI float f_mul(float a, float b) { return __fmul_rn(a, b); }

DI uint64_t umax64(uint64_t a, uint64_t b) { return a > b ? a : b; }

// ---------------------------------------------------------------------------
// 32-bit DPP wave reduces (6-step gfx9 pattern; validated r8-r12).
// ---------------------------------------------------------------------------
template<int CTRL, int RMASK>
DI uint32_t dpp_umax32(uint32_t v) {
  uint32_t o = (uint32_t)__builtin_amdgcn_update_dpp(0, (int)v, CTRL, RMASK, 0xF, false);
  return v > o ? v : o;
}
template<int CTRL, int RMASK>
DI uint32_t dpp_umin32(uint32_t v) {
  uint32_t o = (uint32_t)__builtin_amdgcn_update_dpp(-1, (int)v, CTRL, RMASK, 0xF, false);
  return v < o ? v : o;
}
template<int CTRL, int RMASK>
DI float dpp_fmin32(float v) {
  int o = __builtin_amdgcn_update_dpp(0x7F7FFFFF /*FLT_MAX*/, __float_as_int(v),
                                      CTRL, RMASK, 0xF, false);
  return fminf(v, __int_as_float(o));
}
DI uint32_t wave_umax_bcast32(uint32_t v) {
  v = dpp_umax32<0x111, 0xF>(v);
  v = dpp_umax32<0x112, 0xF>(v);
  v = dpp_umax32<0x114, 0xF>(v);
  v = dpp_umax32<0x118, 0xF>(v);
  v = dpp_umax32<0x142, 0xA>(v);
  v = dpp_umax32<0x143, 0xC>(v);
  return (uint32_t)__builtin_amdgcn_readlane((int)v, 63);
}
DI uint32_t wave_umin_bcast32(uint32_t v) {
  v = dpp_umin32<0x111, 0xF>(v);
  v = dpp_umin32<0x112, 0xF>(v);
  v = dpp_umin32<0x114, 0xF>(v);
  v = dpp_umin32<0x118, 0xF>(v);
  v = dpp_umin32<0x142, 0xA>(v);
  v = dpp_umin32<0x143, 0xC>(v);
  return (uint32_t)__builtin_amdgcn_readlane((int)v, 63);
}
DI float wave_fmin_bcast32(float v) {
  v = dpp_fmin32<0x111, 0xF>(v);
  v = dpp_fmin32<0x112, 0xF>(v);
  v = dpp_fmin32<0x114, 0xF>(v);
  v = dpp_fmin32<0x118, 0xF>(v);
  v = dpp_fmin32<0x142, 0xA>(v);
  v = dpp_fmin32<0x143, 0xC>(v);
  return __int_as_float(__builtin_amdgcn_readlane(__float_as_int(v), 63));
}

// ---------------------------------------------------------------------------
// kNN (r8 verbatim).
// ---------------------------------------------------------------------------
template<int NK>
DI void knn_body(const float* __restrict__ cq, int Nq,
                 const float* __restrict__ ck, int* __restrict__ out,
                 int b, int qbase, float* smem)
{
  constexpr int CPL = NK / 64;
  float* xs = smem;
  float* ys = smem + NK;
  float* zs = smem + 2*NK;
  float* rr = smem + 3*NK;
  const int tid = threadIdx.x;
  for (int i = tid; i < NK; i += 256) {
    float a  = ck[((size_t)b*3 + 0)*NK + i];
    float bb = ck[((size_t)b*3 + 1)*NK + i];
    float c  = ck[((size_t)b*3 + 2)*NK + i];
    xs[i] = a; ys[i] = bb; zs[i] = c;
    rr[i] = f_add(f_add(f_mul(a,a), f_mul(bb,bb)), f_mul(c,c));
  }
  __syncthreads();
  const int lane = tid & 63, w = tid >> 6;
  const int q = qbase + w;
  if (q >= Nq) return;
  float qx = cq[((size_t)b*3 + 0)*Nq + q];
  float qy = cq[((size_t)b*3 + 1)*Nq + q];
  float qz = cq[((size_t)b*3 + 2)*Nq + q];
  float qq = f_add(f_add(f_mul(qx,qx), f_mul(qy,qy)), f_mul(qz,qz));
  float v[CPL];
  #pragma unroll
  for (int j = 0; j < CPL; ++j) {
    int c = j*64 + lane;
    float dot = f_add(f_add(f_mul(qx,xs[c]), f_mul(qy,ys[c])), f_mul(qz,zs[c]));
    v[j] = f_sub(f_add(qq, rr[c]), f_mul(2.0f, dot));
  }
  unsigned mask = (CPL >= 32) ? 0xFFFFFFFFu : ((1u << CPL) - 1u);
  for (int r = 0; r < 16; ++r) {
    float bv = FLT_MAX; int bc = 0x7FFFFFFF;
    #pragma unroll
    for (int j = 0; j < CPL; ++j) {
      float vj = ((mask >> j) & 1u) ? v[j] : FLT_MAX;
      if (vj < bv) { bv = vj; bc = j*64 + lane; }
    }
    float wmin = wave_fmin_bcast32(bv);
    uint32_t cand = (bv == wmin) ? (uint32_t)bc : 0xFFFFFFFFu;
    uint32_t wbc = wave_umin_bcast32(cand);
    if ((wbc & 63) == (uint32_t)lane) mask &= ~(1u << (wbc >> 6));
    if (lane == 0) out[((size_t)b*16 + r)*Nq + q] = (int)wbc;
  }
}

// ---------------------------------------------------------------------------
// FPS (r8 VERBATIM — 4-wave level1; 267-273us measured across rounds).
// ---------------------------------------------------------------------------
__device__ void fps_body(const float* __restrict__ x, int b,
                         int* __restrict__ s1, float* __restrict__ coorq,
                         int* __restrict__ s2, float* __restrict__ coorq2,
                         float* __restrict__ outc, char* smem_raw)
{
  float4*   pts  = (float4*)smem_raw;                       // [2048]
  int*      sel  = (int*)(smem_raw + 32768);                // [512]
  uint64_t* wkey = (uint64_t*)(smem_raw + 32768 + 2048);    // [8]
  const int tid = threadIdx.x, lane = tid & 63, w = tid >> 6;

  for (int i = tid; i < 2048; i += 256)
    pts[i] = make_float4(x[((size_t)b*3 + 0)*2048 + i],
                         x[((size_t)b*3 + 1)*2048 + i],
                         x[((size_t)b*3 + 2)*2048 + i], 0.f);
  __syncthreads();

  float px[8], py[8], pz[8], dl[8];
  #pragma unroll
  for (int j = 0; j < 8; ++j) {
    float4 p = pts[tid + 256*j];
    px[j] = p.x; py[j] = p.y; pz[j] = p.z; dl[j] = 1e10f;
  }

  int far = 0;
  float4 c = pts[0];
  for (int i = 0; i < 512; ++i) {
    if (tid == 0) sel[i] = far;
    float bd = -1.0f; uint32_t bi = 0;
    #pragma unroll
    for (int j = 0; j < 8; ++j) {
      float dx = f_sub(px[j], c.x);
      float dy = f_sub(py[j], c.y);
      float dz = f_sub(pz[j], c.z);
      float d  = f_add(f_add(f_mul(dx,dx), f_mul(dy,dy)), f_mul(dz,dz));
      float nd = fminf(dl[j], d);
      dl[j] = nd;
      if (nd > bd) { bd = nd; bi = (uint32_t)(tid + 256*j); }
    }
    uint32_t db = __float_as_uint(bd);
    uint32_t wd = wave_umax_bcast32(db);
    uint32_t cand = (db == wd) ? bi : 0xFFFFFFFFu;
    uint32_t wi = wave_umin_bcast32(cand);
    if (lane == 0) wkey[(i & 1)*4 + w] = ((uint64_t)wd << 32) | (uint32_t)~wi;
    __syncthreads();
    const uint64_t* wk = wkey + (i & 1)*4;
    uint64_t g = umax64(umax64(wk[0], wk[1]), umax64(wk[2], wk[3]));
    far = (int)~(uint32_t)g;
    c = pts[far];
  }
  __syncthreads();

  int p0 = sel[tid], p1 = sel[tid + 256];
  float4 v0 = pts[p0], v1 = pts[p1];
  s1[b*512 + tid]       = p0;
  s1[b*512 + tid + 256] = p1;
  coorq[((size_t)b*3 + 0)*512 + tid] = v0.x;
  coorq[((size_t)b*3 + 1)*512 + tid] = v0.y;
  coorq[((size_t)b*3 + 2)*512 + tid] = v0.z;
  coorq[((size_t)b*3 + 0)*512 + tid + 256] = v1.x;
  coorq[((size_t)b*3 + 1)*512 + tid + 256] = v1.y;
  coorq[((size_t)b*3 + 2)*512 + tid + 256] = v1.z;
  __syncthreads();
  pts[tid] = v0; pts[tid + 256] = v1;
  __syncthreads();

  if (w == 0) {
    float qx[8], qy[8], qz[8], d2[8];
    #pragma unroll
    for (int j = 0; j < 8; ++j) {
      float4 p = pts[lane + 64*j];
      qx[j] = p.x; qy[j] = p.y; qz[j] = p.z; d2[j] = 1e10f;
    }
    int far2 = 0;
    float cx = pts[0].x, cy = pts[0].y, cz = pts[0].z;
    for (int i = 0; i < 128; ++i) {
      if (lane == 0) sel[i] = far2;
      float bd = -1.0f; uint32_t bi = 0;
      #pragma unroll
      for (int j = 0; j < 8; ++j) {
        float dx = f_sub(qx[j], cx);
        float dy = f_sub(qy[j], cy);
        float dz = f_sub(qz[j], cz);
        float d  = f_add(f_add(f_mul(dx,dx), f_mul(dy,dy)), f_mul(dz,dz));
        float nd = fminf(d2[j], d);
        d2[j] = nd;
        if (nd > bd) { bd = nd; bi = (uint32_t)(lane + 64*j); }
      }
      uint32_t db = __float_as_uint(bd);
      uint32_t wd = wave_umax_bcast32(db);
      uint32_t cand = (db == wd) ? bi : 0xFFFFFFFFu;
      uint32_t wi = wave_umin_bcast32(cand);
      far2 = (int)wi;
      uint32_t js = wi >> 6, ls = wi & 63;
      float sx = qx[0], sy = qy[0], sz = qz[0];
      #pragma unroll
      for (uint32_t t = 1; t < 8; ++t) {
        sx = (js == t) ? qx[t] : sx;
        sy = (js == t) ? qy[t] : sy;
        sz = (js == t) ? qz[t] : sz;
      }
      cx = __int_as_float(__builtin_amdgcn_readlane(__float_as_int(sx), ls));
      cy = __int_as_float(__builtin_amdgcn_readlane(__float_as_int(sy), ls));
      cz = __int_as_float(__builtin_amdgcn_readlane(__float_as_int(sz), ls));
    }
  }
  __syncthreads();
  if (tid < 128) {
    int p = sel[tid];
    float4 v = pts[p];
    s2[b*128 + tid] = p;
    coorq2[((size_t)b*3 + 0)*128 + tid] = v.x;
    coorq2[((size_t)b*3 + 1)*128 + tid] = v.y;
    coorq2[((size_t)b*3 + 2)*128 + tid] = v.z;
    outc[((size_t)b*3 + 0)*128 + tid] = v.x;
    outc[((size_t)b*3 + 1)*128 + tid] = v.y;
    outc[((size_t)b*3 + 2)*128 + tid] = v.z;
  }
}

// ---------------------------------------------------------------------------
// Fused L1 (r12 verbatim, passing): knn1 + in_trans + L1 conv + stats + minmax.
// ---------------------------------------------------------------------------
__device__ void fused_l1_body(const float* __restrict__ x,
                              const float* __restrict__ w_in, const float* __restrict__ b_in,
                              const float* __restrict__ w1,
                              float* __restrict__ ymax1, float* __restrict__ ymin1,
                              float* __restrict__ stats,
                              int b, int S, char* smem_raw)
{
  float* xs = (float*)smem_raw;                 // 2048
  float* ys = xs + 2048;
  float* zs = xs + 4096;
  float* rr = xs + 6144;
  int*   idxloc = (int*)(xs + 8192);            // [16 qi][16 r]
  float* sw1  = (float*)(idxloc + 256);         // 512
  float* winb = sw1 + 512;                      // 32
  float* red  = winb + 32;                      // 32
  const int tid = threadIdx.x, lane = tid & 63, w = tid >> 6;

  for (int i = tid; i < 2048; i += 256) {
    float a  = x[((size_t)b*3 + 0)*2048 + i];
    float bb = x[((size_t)b*3 + 1)*2048 + i];
    float c  = x[((size_t)b*3 + 2)*2048 + i];
    xs[i] = a; ys[i] = bb; zs[i] = c;
    rr[i] = f_add(f_add(f_mul(a,a), f_mul(bb,bb)), f_mul(c,c));
  }
  for (int i = tid; i < 512; i += 256) sw1[i] = w1[i];
  if (tid < 24) winb[tid] = w_in[tid];
  if (tid < 8)  winb[24 + tid] = b_in[tid];
  __syncthreads();

  for (int qq = 0; qq < 4; ++qq) {
    int qi = w*4 + qq;
    int q = S + qi;
    float qx = xs[q], qy = ys[q], qz = zs[q];
    float qqv = f_add(f_add(f_mul(qx,qx), f_mul(qy,qy)), f_mul(qz,qz));
    float v[32];
    #pragma unroll
    for (int j = 0; j < 32; ++j) {
      int c = j*64 + lane;
      float dot = f_add(f_add(f_mul(qx,xs[c]), f_mul(qy,ys[c])), f_mul(qz,zs[c]));
      v[j] = f_sub(f_add(qqv, rr[c]), f_mul(2.0f, dot));
    }
    unsigned mask = 0xFFFFFFFFu;
    for (int r = 0; r < 16; ++r) {
      float bv = FLT_MAX; int bc = 0x7FFFFFFF;
      #pragma unroll
      for (int j = 0; j < 32; ++j) {
        float vj = ((mask >> j) & 1u) ? v[j] : FLT_MAX;
        if (vj < bv) { bv = vj; bc = j*64 + lane; }
      }
      float wmin = wave_fmin_bcast32(bv);
      uint32_t cand = (bv == wmin) ? (uint32_t)bc : 0xFFFFFFFFu;
      uint32_t wbc = wave_umin_bcast32(cand);
      if ((wbc & 63) == (uint32_t)lane) mask &= ~(1u << (wbc >> 6));
      if (lane == 0) idxloc[qi*16 + r] = (int)wbc;
    }
  }
  __syncthreads();

  const int r = tid >> 4, k = tid & 15;
  const int nbr = idxloc[k*16 + r];
  const int ng  = r*128 + (S >> 4);
  float f0n[8], f0q[8], h[8];
  #pragma unroll
  for (int o = 0; o < 8; ++o) {
    f0n[o] = winb[o*3+0]*xs[nbr] + winb[o*3+1]*ys[nbr] + winb[o*3+2]*zs[nbr] + winb[24+o];
    f0q[o] = winb[o*3+0]*xs[ng]  + winb[o*3+1]*ys[ng]  + winb[o*3+2]*zs[ng]  + winb[24+o];
    h[o] = f0n[o] - f0q[o];
  }
  float gsum[4] = {0.f,0.f,0.f,0.f}, gsq[4] = {0.f,0.f,0.f,0.f};
  float* ymx = ymax1 + ((size_t)b*2048 + ng)*32;
  float* ymn = ymin1 + ((size_t)b*2048 + ng)*32;
  for (int o = 0; o < 32; ++o) {
    const float4* wr = (const float4*)(sw1 + o*16);
    float4 wa = wr[0], wb4 = wr[1], wc = wr[2], wd = wr[3];
    float acc = wa.x*h[0]+wa.y*h[1]+wa.z*h[2]+wa.w*h[3]
              + wb4.x*h[4]+wb4.y*h[5]+wb4.z*h[6]+wb4.w*h[7]
              + wc.x*f0q[0]+wc.y*f0q[1]+wc.z*f0q[2]+wc.w*f0q[3]
              + wd.x*f0q[4]+wd.y*f0q[5]+wd.z*f0q[6]+wd.w*f0q[7];
    float mx = acc, mn = acc;
    #pragma unroll
    for (int off = 1; off < 16; off <<= 1) {
      mx = fmaxf(mx, __shfl_xor(mx, off));
      mn = fminf(mn, __shfl_xor(mn, off));
    }
    if (k == 0) { ymx[o] = mx; ymn[o] = mn; }
    int g = o >> 3;
    gsum[g] += acc; gsq[g] += acc*acc;
  }
  #pragma unroll
  for (int g = 0; g < 4; ++g) {
    #pragma unroll
    for (int off = 1; off < 64; off <<= 1) {
      gsum[g] += __shfl_xor(gsum[g], off);
      gsq[g]  += __shfl_xor(gsq[g], off);
    }
  }
  if (lane == 0) {
    #pragma unroll
    for (int g = 0; g < 4; ++g) { red[w*8 + g] = gsum[g]; red[w*8 + 4 + g] = gsq[g]; }
  }
  __syncthreads();
  if (tid == 0) {
    #pragma unroll
    for (int g = 0; g < 4; ++g) {
      float s0  = (red[g] + red[8+g]) + (red[16+g] + red[24+g]);
      float s1v = (red[4+g] + red[12+g]) + (red[20+g] + red[28+g]);
      atomicAdd(stats + (b*4 + g)*2,     s0);
      atomicAdd(stats + (b*4 + g)*2 + 1, s1v);
    }
  }
}

// ---------------------------------------------------------------------------
// mega1: blocks 0-7 FPS; blocks 8..1031 fused L1.
// ---------------------------------------------------------------------------
__global__ __launch_bounds__(256) void mega1(
    const float* __restrict__ x, const float* __restrict__ w_in, const float* __restrict__ b_in,
    const float* __restrict__ w1,
    float* __restrict__ ymax1, float* __restrict__ ymin1, float* __restrict__ stats,
    int* __restrict__ s1, float* __restrict__ coorq,
    int* __restrict__ s2, float* __restrict__ coorq2, float* __restrict__ outc)
{
  __shared__ char smem_raw[36352] __attribute__((aligned(16)));
  const int bid = blockIdx.x;
  if (bid < 8) {
    fps_body(x, bid, s1, coorq, s2, coorq2, outc, smem_raw);
  } else {
    int vb = bid - 8;
    fused_l1_body(x, w_in, b_in, w1, ymax1, ymin1, stats,
                  vb >> 7, (vb & 127)*16, smem_raw);
  }
}

// ---------------------------------------------------------------------------
// mega2: knn2 + knn3 + knn4 only.
// ---------------------------------------------------------------------------
__global__ __launch_bounds__(256) void mega2(
    const float* __restrict__ x, const float* __restrict__ coorq,
    const float* __restrict__ coorq2,
    int* __restrict__ idx2, int* __restrict__ idx3, int* __restrict__ idx4)
{
  __shared__ char smem_raw[32768] __attribute__((aligned(16)));
  const int bid = blockIdx.x;
  if (bid < 1024) {
    knn_body<2048>(coorq, 512, x, idx2, bid >> 7, (bid & 127)*4, (float*)smem_raw);
  } else if (bid < 2048) {
    int v = bid - 1024;
    knn_body<512>(coorq, 512, coorq, idx3, v >> 7, (v & 127)*4, (float*)smem_raw);
  } else {
    int v = bid - 2048;
    knn_body<512>(coorq2, 128, coorq, idx4, v >> 5, (v & 31)*4, (float*)smem_raw);
  }
}

// ---------------------------------------------------------------------------
// conv_p1mm: edge conv reading previous layer via (ymax,ymin,stats,g,be)
// on-the-fly dequant (exact GN+lrelu op order of the passing p2), storing
// per-(n,o) ymax/ymin + GN stats. TN: output layout [b][n][o] vs [b][o][n].
// ---------------------------------------------------------------------------
template<int C, int O, int NQ, int NKp, bool TN>
DI void conv_p1mm_body(
    const float* __restrict__ ymaxP, const float* __restrict__ yminP,
    const float* __restrict__ statsP,
    const float* __restrict__ gP, const float* __restrict__ beP,
    const int* __restrict__ qg, const int* __restrict__ knn_idx,
    const float* __restrict__ w,
    float* __restrict__ ymaxO, float* __restrict__ yminO, float* __restrict__ statsO,
    int nt, int g, int b, float* smem)
{
  constexpr int GRP = O/4;
  const float cntP = (float)((C/4) * NKp * 16);
  const int tid = threadIdx.x;
  float* sxq = smem;                 // 16*C
  float* sw  = sxq + 16*C;           // GRP*2*C
  float* dmu = sw + GRP*2*C;         // C
  float* drs = dmu + C;              // C
  float* dga = drs + C;              // C
  float* dbe = dga + C;              // C
  float* red = dbe + C;              // 8

  // phase 1: weights + per-channel dequant params of previous layer
  for (int i = tid; i < GRP*2*C; i += 256) sw[i] = w[(size_t)g*GRP*2*C + i];
  for (int i = tid; i < C; i += 256) {
    int gp = i / (C/4);
    float s0 = statsP[(b*4+gp)*2], s1v = statsP[(b*4+gp)*2+1];
    float mu = s0 / cntP;
    float var = fmaxf(s1v/cntP - mu*mu, 0.f);
    dmu[i] = mu; drs[i] = 1.f/sqrtf(var + 1e-5f);
    dga[i] = gP[i]; dbe[i] = beP[i];
  }
  __syncthreads();

  // phase 2: stage dequanted query rows
  for (int i = tid; i < 16*C; i += 256) {
    int nn = i / C, ci = i % C;
    int q = nt*16 + nn;
    int src = qg ? qg[b*NQ + q] : q;
    float vmx = ymaxP[((size_t)b*NKp + src)*C + ci];
    float vmn = yminP[((size_t)b*NKp + src)*C + ci];
    float ga = dga[ci];
    float v = (ga >= 0.f) ? vmx : vmn;
    float a = ((v - dmu[ci])*drs[ci])*ga + dbe[ci];
    sxq[i] = a >= 0.f ? a : 0.2f*a;
  }
  __syncthreads();

  const int nloc = tid >> 4, kk = tid & 15;
  const int n = nt*16 + nloc;
  const int flat = n*16 + kk;
  const int r = flat / NQ, s = flat % NQ;
  const int nbr = knn_idx[((size_t)b*16 + r)*NQ + s];

  float xqv[C], h1[C];
  {
    const float4* xq4 = (const float4*)(sxq + nloc*C);
    const float4* mx4 = (const float4*)(ymaxP + ((size_t)b*NKp + nbr)*C);
    const float4* mn4 = (const float4*)(yminP + ((size_t)b*NKp + nbr)*C);
    const float4* pmu = (const float4*)dmu;
    const float4* prs = (const float4*)drs;
    const float4* pga = (const float4*)dga;
    const float4* pbe = (const float4*)dbe;
    #pragma unroll
    for (int c4 = 0; c4 < C/4; ++c4) {
      float4 a = xq4[c4], vx = mx4[c4], vn = mn4[c4];
      float4 mu = pmu[c4], rs = prs[c4], ga = pga[c4], be = pbe[c4];
      float v0 = (ga.x >= 0.f) ? vx.x : vn.x;
      float v1 = (ga.y >= 0.f) ? vx.y : vn.y;
      float v2 = (ga.z >= 0.f) ? vx.z : vn.z;
      float v3 = (ga.w >= 0.f) ? vx.w : vn.w;
      float f0 = ((v0 - mu.x)*rs.x)*ga.x + be.x; f0 = f0 >= 0.f ? f0 : 0.2f*f0;
      float f1 = ((v1 - mu.y)*rs.y)*ga.y + be.y; f1 = f1 >= 0.f ? f1 : 0.2f*f1;
      float f2 = ((v2 - mu.z)*rs.z)*ga.z + be.z; f2 = f2 >= 0.f ? f2 : 0.2f*f2;
      float f3 = ((v3 - mu.w)*rs.w)*ga.w + be.w; f3 = f3 >= 0.f ? f3 : 0.2f*f3;
      xqv[4*c4+0] = a.x; h1[4*c4+0] = f0 - a.x;
      xqv[4*c4+1] = a.y; h1[4*c4+1] = f1 - a.y;
      xqv[4*c4+2] = a.z; h1[4*c4+2] = f2 - a.z;
      xqv[4*c4+3] = a.w; h1[4*c4+3] = f3 - a.w;
    }
  }
  float lsum = 0.f, lsq = 0.f;
  for (int o = 0; o < GRP; ++o) {
    const float4* wr = (const float4*)(sw + o*2*C);
    float acc = 0.f;
    #pragma unroll
    for (int c4 = 0; c4 < C/4; ++c4) {
      float4 w4 = wr[c4];
      acc += w4.x*h1[4*c4] + w4.y*h1[4*c4+1] + w4.z*h1[4*c4+2] + w4.w*h1[4*c4+3];
    }
    #pragma unroll
    for (int c4 = 0; c4 < C/4; ++c4) {
      float4 w4 = wr[C/4 + c4];
      acc += w4.x*xqv[4*c4] + w4.y*xqv[4*c4+1] + w4.z*xqv[4*c4+2] + w4.w*xqv[4*c4+3];
    }
    float mx = acc, mn = acc;
    #pragma unroll
    for (int off = 1; off < 16; off <<= 1) {
      mx = fmaxf(mx, __shfl_xor(mx, off));
      mn = fminf(mn, __shfl_xor(mn, off));
    }
    if (kk == 0) {
      int og = g*GRP + o;
      size_t idx = TN ? (((size_t)b*NQ + n)*O + og) : (((size_t)b*O + og)*NQ + n);
      ymaxO[idx] = mx; yminO[idx] = mn;
    }
    lsum += acc; lsq += acc*acc;
  }
  #pragma unroll
  for (int off = 32; off; off >>= 1) {
    lsum += __shfl_xor(lsum, off);
    lsq  += __shfl_xor(lsq, off);
  }
  const int lane = tid & 63, wvid = tid >> 6;
  if (lane == 0) { red[wvid] = lsum; red[4+wvid] = lsq; }
  __syncthreads();
  if (tid == 0) {
    float s0  = (red[0]+red[1]) + (red[2]+red[3]);
    float s1v = (red[4]+red[5]) + (red[6]+red[7]);
    atomicAdd(statsO + ((size_t)b*4 + g)*2,     s0);
    atomicAdd(statsO + ((size_t)b*4 + g)*2 + 1, s1v);
  }
}

template<int C, int O, int NQ, int NKp, bool TN>
__global__ __launch_bounds__(256) void conv_p1mm(
    const float* __restrict__ ymaxP, const float* __restrict__ yminP,
    const float* __restrict__ statsP,
    const float* __restrict__ gP, const float* __restrict__ beP,
    const int* __restrict__ qg, const int* __restrict__ knn_idx,
    const float* __restrict__ w,
    float* __restrict__ ymaxO, float* __restrict__ yminO, float* __restrict__ statsO)
{
  __shared__ float smem_f[16*C + (O/4)*2*C + 4*C + 8];
  conv_p1mm_body<C, O, NQ, NKp, TN>(ymaxP, yminP, statsP, gP, beP, qg, knn_idx,
                                    w, ymaxO, yminO, statsO,
                                    blockIdx.x, blockIdx.y, blockIdx.z, smem_f);
}

// Final: L4 GN + lrelu from minmax (stored [b][o][n] -> coalesced).
__global__ __launch_bounds__(256) void l4fin(
    const float* __restrict__ ymax4, const float* __restrict__ ymin4,
    const float* __restrict__ stats4,
    const float* __restrict__ g4, const float* __restrict__ be4,
    float* __restrict__ f4)
{
  int t = blockIdx.x*256 + threadIdx.x;     // 131072 = [b][o][n]
  int b = t >> 14;
  int o = (t >> 7) & 127;
  int g = o >> 5;
  const float cnt = 32.f*128.f*16.f;
  float s0 = stats4[(b*4+g)*2], s1v = stats4[(b*4+g)*2+1];
  float mu = s0 / cnt;
  float var = fmaxf(s1v/cnt - mu*mu, 0.f);
  float rs = 1.f/sqrtf(var + 1e-5f);
  float ga = g4[o], be = be4[o];
  float v = (ga >= 0.f) ? ymax4[t] : ymin4[t];
  float a = ((v - mu)*rs)*ga + be;
  f4[t] = a >= 0.f ? a : 0.2f*a;
}

// ---------------------------------------------------------------------------
extern "C" void kernel_launch(void* const* d_in, const int* in_sizes, int n_in,
                              void* d_out, int out_size, void* d_ws, size_t ws_size,
                              hipStream_t stream)
{
  (void)in_sizes; (void)n_in; (void)out_size; (void)ws_size;
  const float* x    = (const float*)d_in[0];
  const float* w_in = (const float*)d_in[1];
  const float* b_in = (const float*)d_in[2];
  const float* w1   = (const float*)d_in[3];
  const float* g1   = (const float*)d_in[4];
  const float* be1  = (const float*)d_in[5];
  const float* w2   = (const float*)d_in[6];
  const float* g2   = (const float*)d_in[7];
  const float* be2  = (const float*)d_in[8];
  const float* w3   = (const float*)d_in[9];
  const float* g3   = (const float*)d_in[10];
  const float* be3  = (const float*)d_in[11];
  const float* w4   = (const float*)d_in[12];
  const float* g4   = (const float*)d_in[13];
  const float* be4  = (const float*)d_in[14];

  float* ws = (float*)d_ws;
  float* stats  = ws;                      // 256 (L1..L4 at +0,+64,+128,+192)
  float* ymax1  = ws + 256;                // [8,2048,32] -> 524544
  float* ymin1  = ws + 524544;             //             -> 1048832
  int*   s1     = (int*)(ws + 1048832);    // [8,512]     -> 1052928
  float* coorq  = ws + 1052928;            // [8,3,512]   -> 1065216
  int*   idx2   = (int*)(ws + 1065216);    // [8,16,512]  -> 1130752
  float* ymax2  = ws + 1130752;            // [8,512,64]  -> 1392896
  float* ymin2  = ws + 1392896;            //             -> 1655040
  int*   idx3   = (int*)(ws + 1655040);    // [8,16,512]  -> 1720576
  float* ymax3  = ws + 1720576;            // [8,512,64]  -> 1982720
  float* ymin3  = ws + 1982720;            //             -> 2244864
  int*   s2     = (int*)(ws + 2244864);    // [8,128]     -> 2245888
  float* coorq2 = ws + 2245888;            // [8,3,128]   -> 2248960
  int*   idx4   = (int*)(ws + 2248960);    // [8,16,128]  -> 2265344
  float* ymax4  = ws + 2265344;            // [8,128,128] -> 2396416
  float* ymin4  = ws + 2396416;            //             -> 2527488

  float* outc = (float*)d_out;             // [8,3,128]
  float* f4   = (float*)d_out + 3072;      // [8,128,128]

  hipMemsetAsync(stats, 0, 256*sizeof(float), stream);

  // FPS + fused L1 (knn1 + in_trans + conv + stats + minmax).
  mega1<<<dim3(1032), 256, 0, stream>>>(
      x, w_in, b_in, w1, ymax1, ymin1, stats, s1, coorq, s2, coorq2, outc);

  // knn2 + knn3 + knn4.
  mega2<<<dim3(2304), 256, 0, stream>>>(x, coorq, coorq2, idx2, idx3, idx4);

  // L2: C=32 -> O=64, Nq=512, prev rows 2048 (L1), queries gathered by s1.
  conv_p1mm<32, 64, 512, 2048, true><<<dim3(32, 4, 8), 256, 0, stream>>>(
      ymax1, ymin1, stats, g1, be1, s1, idx2, w2, ymax2, ymin2, stats + 64);

  // L3: C=64 -> O=64, Nq=512, prev rows 512 (L2).
  conv_p1mm<64, 64, 512, 512, true><<<dim3(32, 4, 8), 256, 0, stream>>>(
      ymax2, ymin2, stats + 64, g2, be2, nullptr, idx3, w3, ymax3, ymin3, stats + 128);

  // L4: C=64 -> O=128, Nq=128, prev rows 512 (L3), queries gathered by s2.
  conv_p1mm<64, 128, 128, 512, false><<<dim3(8, 4, 8), 256, 0, stream>>>(
      ymax3, ymin3, stats + 128, g3, be3, s2, idx4, w4, ymax4, ymin4, stats + 192);

  // Final L4 GN + lrelu.
  l4fin<<<dim3(512), 256, 0, stream>>>(ymax4, ymin4, stats + 192, g4, be4, f4);
}

// Round 14
// 418.803 us; speedup vs baseline: 2.2349x; 1.0285x over previous
//
#include <hip/hip_runtime.h>
#include <float.h>
#include <stdint.h>

// DGCNN_Grouper forward on MI355X. B=8, N=2048, K=16, fp32.
// r13 architecture. Round 14 change: FPS level-1 uses contiguous per-lane
// assignment (idx = tid*8+j) so the tie-break collapses to ballot+ffs+readlane
// (r9-validated semantics), and s_setprio(1) wraps the FPS loops (T5: FPS is
// latency-bound and shares CUs with throughput-heavy fused-L1 blocks).

#define DI __device__ __forceinline__
DI float f_add(float a, float b) { return __fadd_rn(a, b); }
DI float f_sub(float a, float b) { return __fsub_rn(a, b); }
DI float f_mul(float a, float b) { return __fmul_rn(a, b); }

DI uint64_t umax64(uint64_t a, uint64_t b) { return a > b ? a : b; }

// ---------------------------------------------------------------------------
// 32-bit DPP wave reduces (6-step gfx9 pattern; validated r8-r13).
// ---------------------------------------------------------------------------
template<int CTRL, int RMASK>
DI uint32_t dpp_umax32(uint32_t v) {
  uint32_t o = (uint32_t)__builtin_amdgcn_update_dpp(0, (int)v, CTRL, RMASK, 0xF, false);
  return v > o ? v : o;
}
template<int CTRL, int RMASK>
DI uint32_t dpp_umin32(uint32_t v) {
  uint32_t o = (uint32_t)__builtin_amdgcn_update_dpp(-1, (int)v, CTRL, RMASK, 0xF, false);
  return v < o ? v : o;
}
template<int CTRL, int RMASK>
DI float dpp_fmin32(float v) {
  int o = __builtin_amdgcn_update_dpp(0x7F7FFFFF /*FLT_MAX*/, __float_as_int(v),
                                      CTRL, RMASK, 0xF, false);
  return fminf(v, __int_as_float(o));
}
DI uint32_t wave_umax_bcast32(uint32_t v) {
  v = dpp_umax32<0x111, 0xF>(v);
  v = dpp_umax32<0x112, 0xF>(v);
  v = dpp_umax32<0x114, 0xF>(v);
  v = dpp_umax32<0x118, 0xF>(v);
  v = dpp_umax32<0x142, 0xA>(v);
  v = dpp_umax32<0x143, 0xC>(v);
  return (uint32_t)__builtin_amdgcn_readlane((int)v, 63);
}
DI uint32_t wave_umin_bcast32(uint32_t v) {
  v = dpp_umin32<0x111, 0xF>(v);
  v = dpp_umin32<0x112, 0xF>(v);
  v = dpp_umin32<0x114, 0xF>(v);
  v = dpp_umin32<0x118, 0xF>(v);
  v = dpp_umin32<0x142, 0xA>(v);
  v = dpp_umin32<0x143, 0xC>(v);
  return (uint32_t)__builtin_amdgcn_readlane((int)v, 63);
}
DI float wave_fmin_bcast32(float v) {
  v = dpp_fmin32<0x111, 0xF>(v);
  v = dpp_fmin32<0x112, 0xF>(v);
  v = dpp_fmin32<0x114, 0xF>(v);
  v = dpp_fmin32<0x118, 0xF>(v);
  v = dpp_fmin32<0x142, 0xA>(v);
  v = dpp_fmin32<0x143, 0xC>(v);
  return __int_as_float(__builtin_amdgcn_readlane(__float_as_int(v), 63));
}

// ---------------------------------------------------------------------------
// kNN (r8 verbatim).
// ---------------------------------------------------------------------------
template<int NK>
DI void knn_body(const float* __restrict__ cq, int Nq,
                 const float* __restrict__ ck, int* __restrict__ out,
                 int b, int qbase, float* smem)
{
  constexpr int CPL = NK / 64;
  float* xs = smem;
  float* ys = smem + NK;
  float* zs = smem + 2*NK;
  float* rr = smem + 3*NK;
  const int tid = threadIdx.x;
  for (int i = tid; i < NK; i += 256) {
    float a  = ck[((size_t)b*3 + 0)*NK + i];
    float bb = ck[((size_t)b*3 + 1)*NK + i];
    float c  = ck[((size_t)b*3 + 2)*NK + i];
    xs[i] = a; ys[i] = bb; zs[i] = c;
    rr[i] = f_add(f_add(f_mul(a,a), f_mul(bb,bb)), f_mul(c,c));
  }
  __syncthreads();
  const int lane = tid & 63, w = tid >> 6;
  const int q = qbase + w;
  if (q >= Nq) return;
  float qx = cq[((size_t)b*3 + 0)*Nq + q];
  float qy = cq[((size_t)b*3 + 1)*Nq + q];
  float qz = cq[((size_t)b*3 + 2)*Nq + q];
  float qq = f_add(f_add(f_mul(qx,qx), f_mul(qy,qy)), f_mul(qz,qz));
  float v[CPL];
  #pragma unroll
  for (int j = 0; j < CPL; ++j) {
    int c = j*64 + lane;
    float dot = f_add(f_add(f_mul(qx,xs[c]), f_mul(qy,ys[c])), f_mul(qz,zs[c]));
    v[j] = f_sub(f_add(qq, rr[c]), f_mul(2.0f, dot));
  }
  unsigned mask = (CPL >= 32) ? 0xFFFFFFFFu : ((1u << CPL) - 1u);
  for (int r = 0; r < 16; ++r) {
    float bv = FLT_MAX; int bc = 0x7FFFFFFF;
    #pragma unroll
    for (int j = 0; j < CPL; ++j) {
      float vj = ((mask >> j) & 1u) ? v[j] : FLT_MAX;
      if (vj < bv) { bv = vj; bc = j*64 + lane; }
    }
    float wmin = wave_fmin_bcast32(bv);
    uint32_t cand = (bv == wmin) ? (uint32_t)bc : 0xFFFFFFFFu;
    uint32_t wbc = wave_umin_bcast32(cand);
    if ((wbc & 63) == (uint32_t)lane) mask &= ~(1u << (wbc >> 6));
    if (lane == 0) out[((size_t)b*16 + r)*Nq + q] = (int)wbc;
  }
}

// ---------------------------------------------------------------------------
// FPS. Level 1: 4 waves, CONTIGUOUS assignment idx = tid*8+j (strict-> scan
// picks lowest j => lowest global idx per thread; min tie lane = min global
// idx). Tie-break = ballot+ffs+readlane (replaces 6-DPP umin chain).
// Cross-wave via packed wkey (unchanged). setprio(1) wraps both loops.
// Level 2: r8-verbatim. Distance math bit-identical to reference.
// ---------------------------------------------------------------------------
__device__ void fps_body(const float* __restrict__ x, int b,
                         int* __restrict__ s1, float* __restrict__ coorq,
                         int* __restrict__ s2, float* __restrict__ coorq2,
                         float* __restrict__ outc, char* smem_raw)
{
  float4*   pts  = (float4*)smem_raw;                       // [2048]
  int*      sel  = (int*)(smem_raw + 32768);                // [512]
  uint64_t* wkey = (uint64_t*)(smem_raw + 32768 + 2048);    // [8]
  const int tid = threadIdx.x, lane = tid & 63, w = tid >> 6;

  for (int i = tid; i < 2048; i += 256)
    pts[i] = make_float4(x[((size_t)b*3 + 0)*2048 + i],
                         x[((size_t)b*3 + 1)*2048 + i],
                         x[((size_t)b*3 + 2)*2048 + i], 0.f);
  __syncthreads();

  float px[8], py[8], pz[8], dl[8];
  #pragma unroll
  for (int j = 0; j < 8; ++j) {
    float4 p = pts[tid*8 + j];     // contiguous; one-time conflicted read OK
    px[j] = p.x; py[j] = p.y; pz[j] = p.z; dl[j] = 1e10f;
  }

  __builtin_amdgcn_s_setprio(1);
  int far = 0;
  float4 c = pts[0];
  for (int i = 0; i < 512; ++i) {
    if (tid == 0) sel[i] = far;
    float bd = -1.0f; int bj = 0;
    #pragma unroll
    for (int j = 0; j < 8; ++j) {
      float dx = f_sub(px[j], c.x);
      float dy = f_sub(py[j], c.y);
      float dz = f_sub(pz[j], c.z);
      float d  = f_add(f_add(f_mul(dx,dx), f_mul(dy,dy)), f_mul(dz,dz));
      float nd = fminf(dl[j], d);
      dl[j] = nd;
      if (nd > bd) { bd = nd; bj = j; }   // strict >: lowest j (lowest idx) wins
    }
    uint32_t db = __float_as_uint(bd);            // bd >= +0 => u32 order == f32
    uint32_t wd = wave_umax_bcast32(db);
    uint64_t ball = __ballot(db == wd);
    int wl = __ffsll((unsigned long long)ball) - 1;   // min lane = min global idx
    int wbj = __builtin_amdgcn_readlane(bj, wl);
    uint32_t wbi = (uint32_t)(((w*64 + wl)*8) + wbj);
    if (lane == 0) wkey[(i & 1)*4 + w] = ((uint64_t)wd << 32) | (uint32_t)~wbi;
    __syncthreads();
    const uint64_t* wk = wkey + (i & 1)*4;
    uint64_t g = umax64(umax64(wk[0], wk[1]), umax64(wk[2], wk[3]));
    far = (int)~(uint32_t)g;
    c = pts[far];
  }
  __builtin_amdgcn_s_setprio(0);
  __syncthreads();

  int p0 = sel[tid], p1 = sel[tid + 256];
  float4 v0 = pts[p0], v1 = pts[p1];
  s1[b*512 + tid]       = p0;
  s1[b*512 + tid + 256] = p1;
  coorq[((size_t)b*3 + 0)*512 + tid] = v0.x;
  coorq[((size_t)b*3 + 1)*512 + tid] = v0.y;
  coorq[((size_t)b*3 + 2)*512 + tid] = v0.z;
  coorq[((size_t)b*3 + 0)*512 + tid + 256] = v1.x;
  coorq[((size_t)b*3 + 1)*512 + tid + 256] = v1.y;
  coorq[((size_t)b*3 + 2)*512 + tid + 256] = v1.z;
  __syncthreads();
  pts[tid] = v0; pts[tid + 256] = v1;
  __syncthreads();

  if (w == 0) {
    __builtin_amdgcn_s_setprio(1);
    float qx[8], qy[8], qz[8], d2[8];
    #pragma unroll
    for (int j = 0; j < 8; ++j) {
      float4 p = pts[lane + 64*j];
      qx[j] = p.x; qy[j] = p.y; qz[j] = p.z; d2[j] = 1e10f;
    }
    int far2 = 0;
    float cx = pts[0].x, cy = pts[0].y, cz = pts[0].z;
    for (int i = 0; i < 128; ++i) {
      if (lane == 0) sel[i] = far2;
      float bd = -1.0f; uint32_t bi = 0;
      #pragma unroll
      for (int j = 0; j < 8; ++j) {
        float dx = f_sub(qx[j], cx);
        float dy = f_sub(qy[j], cy);
        float dz = f_sub(qz[j], cz);
        float d  = f_add(f_add(f_mul(dx,dx), f_mul(dy,dy)), f_mul(dz,dz));
        float nd = fminf(d2[j], d);
        d2[j] = nd;
        if (nd > bd) { bd = nd; bi = (uint32_t)(lane + 64*j); }
      }
      uint32_t db = __float_as_uint(bd);
      uint32_t wd = wave_umax_bcast32(db);
      uint32_t cand = (db == wd) ? bi : 0xFFFFFFFFu;
      uint32_t wi = wave_umin_bcast32(cand);
      far2 = (int)wi;
      uint32_t js = wi >> 6, ls = wi & 63;
      float sx = qx[0], sy = qy[0], sz = qz[0];
      #pragma unroll
      for (uint32_t t = 1; t < 8; ++t) {
        sx = (js == t) ? qx[t] : sx;
        sy = (js == t) ? qy[t] : sy;
        sz = (js == t) ? qz[t] : sz;
      }
      cx = __int_as_float(__builtin_amdgcn_readlane(__float_as_int(sx), ls));
      cy = __int_as_float(__builtin_amdgcn_readlane(__float_as_int(sy), ls));
      cz = __int_as_float(__builtin_amdgcn_readlane(__float_as_int(sz), ls));
    }
    __builtin_amdgcn_s_setprio(0);
  }
  __syncthreads();
  if (tid < 128) {
    int p = sel[tid];
    float4 v = pts[p];
    s2[b*128 + tid] = p;
    coorq2[((size_t)b*3 + 0)*128 + tid] = v.x;
    coorq2[((size_t)b*3 + 1)*128 + tid] = v.y;
    coorq2[((size_t)b*3 + 2)*128 + tid] = v.z;
    outc[((size_t)b*3 + 0)*128 + tid] = v.x;
    outc[((size_t)b*3 + 1)*128 + tid] = v.y;
    outc[((size_t)b*3 + 2)*128 + tid] = v.z;
  }
}

// ---------------------------------------------------------------------------
// Fused L1 (r12 verbatim, passing).
// ---------------------------------------------------------------------------
__device__ void fused_l1_body(const float* __restrict__ x,
                              const float* __restrict__ w_in, const float* __restrict__ b_in,
                              const float* __restrict__ w1,
                              float* __restrict__ ymax1, float* __restrict__ ymin1,
                              float* __restrict__ stats,
                              int b, int S, char* smem_raw)
{
  float* xs = (float*)smem_raw;                 // 2048
  float* ys = xs + 2048;
  float* zs = xs + 4096;
  float* rr = xs + 6144;
  int*   idxloc = (int*)(xs + 8192);            // [16 qi][16 r]
  float* sw1  = (float*)(idxloc + 256);         // 512
  float* winb = sw1 + 512;                      // 32
  float* red  = winb + 32;                      // 32
  const int tid = threadIdx.x, lane = tid & 63, w = tid >> 6;

  for (int i = tid; i < 2048; i += 256) {
    float a  = x[((size_t)b*3 + 0)*2048 + i];
    float bb = x[((size_t)b*3 + 1)*2048 + i];
    float c  = x[((size_t)b*3 + 2)*2048 + i];
    xs[i] = a; ys[i] = bb; zs[i] = c;
    rr[i] = f_add(f_add(f_mul(a,a), f_mul(bb,bb)), f_mul(c,c));
  }
  for (int i = tid; i < 512; i += 256) sw1[i] = w1[i];
  if (tid < 24) winb[tid] = w_in[tid];
  if (tid < 8)  winb[24 + tid] = b_in[tid];
  __syncthreads();

  for (int qq = 0; qq < 4; ++qq) {
    int qi = w*4 + qq;
    int q = S + qi;
    float qx = xs[q], qy = ys[q], qz = zs[q];
    float qqv = f_add(f_add(f_mul(qx,qx), f_mul(qy,qy)), f_mul(qz,qz));
    float v[32];
    #pragma unroll
    for (int j = 0; j < 32; ++j) {
      int c = j*64 + lane;
      float dot = f_add(f_add(f_mul(qx,xs[c]), f_mul(qy,ys[c])), f_mul(qz,zs[c]));
      v[j] = f_sub(f_add(qqv, rr[c]), f_mul(2.0f, dot));
    }
    unsigned mask = 0xFFFFFFFFu;
    for (int r = 0; r < 16; ++r) {
      float bv = FLT_MAX; int bc = 0x7FFFFFFF;
      #pragma unroll
      for (int j = 0; j < 32; ++j) {
        float vj = ((mask >> j) & 1u) ? v[j] : FLT_MAX;
        if (vj < bv) { bv = vj; bc = j*64 + lane; }
      }
      float wmin = wave_fmin_bcast32(bv);
      uint32_t cand = (bv == wmin) ? (uint32_t)bc : 0xFFFFFFFFu;
      uint32_t wbc = wave_umin_bcast32(cand);
      if ((wbc & 63) == (uint32_t)lane) mask &= ~(1u << (wbc >> 6));
      if (lane == 0) idxloc[qi*16 + r] = (int)wbc;
    }
  }
  __syncthreads();

  const int r = tid >> 4, k = tid & 15;
  const int nbr = idxloc[k*16 + r];
  const int ng  = r*128 + (S >> 4);
  float f0n[8], f0q[8], h[8];
  #pragma unroll
  for (int o = 0; o < 8; ++o) {
    f0n[o] = winb[o*3+0]*xs[nbr] + winb[o*3+1]*ys[nbr] + winb[o*3+2]*zs[nbr] + winb[24+o];
    f0q[o] = winb[o*3+0]*xs[ng]  + winb[o*3+1]*ys[ng]  + winb[o*3+2]*zs[ng]  + winb[24+o];
    h[o] = f0n[o] - f0q[o];
  }
  float gsum[4] = {0.f,0.f,0.f,0.f}, gsq[4] = {0.f,0.f,0.f,0.f};
  float* ymx = ymax1 + ((size_t)b*2048 + ng)*32;
  float* ymn = ymin1 + ((size_t)b*2048 + ng)*32;
  for (int o = 0; o < 32; ++o) {
    const float4* wr = (const float4*)(sw1 + o*16);
    float4 wa = wr[0], wb4 = wr[1], wc = wr[2], wd = wr[3];
    float acc = wa.x*h[0]+wa.y*h[1]+wa.z*h[2]+wa.w*h[3]
              + wb4.x*h[4]+wb4.y*h[5]+wb4.z*h[6]+wb4.w*h[7]
              + wc.x*f0q[0]+wc.y*f0q[1]+wc.z*f0q[2]+wc.w*f0q[3]
              + wd.x*f0q[4]+wd.y*f0q[5]+wd.z*f0q[6]+wd.w*f0q[7];
    float mx = acc, mn = acc;
    #pragma unroll
    for (int off = 1; off < 16; off <<= 1) {
      mx = fmaxf(mx, __shfl_xor(mx, off));
      mn = fminf(mn, __shfl_xor(mn, off));
    }
    if (k == 0) { ymx[o] = mx; ymn[o] = mn; }
    int g = o >> 3;
    gsum[g] += acc; gsq[g] += acc*acc;
  }
  #pragma unroll
  for (int g = 0; g < 4; ++g) {
    #pragma unroll
    for (int off = 1; off < 64; off <<= 1) {
      gsum[g] += __shfl_xor(gsum[g], off);
      gsq[g]  += __shfl_xor(gsq[g], off);
    }
  }
  if (lane == 0) {
    #pragma unroll
    for (int g = 0; g < 4; ++g) { red[w*8 + g] = gsum[g]; red[w*8 + 4 + g] = gsq[g]; }
  }
  __syncthreads();
  if (tid == 0) {
    #pragma unroll
    for (int g = 0; g < 4; ++g) {
      float s0  = (red[g] + red[8+g]) + (red[16+g] + red[24+g]);
      float s1v = (red[4+g] + red[12+g]) + (red[20+g] + red[28+g]);
      atomicAdd(stats + (b*4 + g)*2,     s0);
      atomicAdd(stats + (b*4 + g)*2 + 1, s1v);
    }
  }
}

// ---------------------------------------------------------------------------
// mega1: blocks 0-7 FPS; blocks 8..1031 fused L1.
// ---------------------------------------------------------------------------
__global__ __launch_bounds__(256) void mega1(
    const float* __restrict__ x, const float* __restrict__ w_in, const float* __restrict__ b_in,
    const float* __restrict__ w1,
    float* __restrict__ ymax1, float* __restrict__ ymin1, float* __restrict__ stats,
    int* __restrict__ s1, float* __restrict__ coorq,
    int* __restrict__ s2, float* __restrict__ coorq2, float* __restrict__ outc)
{
  __shared__ char smem_raw[36352] __attribute__((aligned(16)));
  const int bid = blockIdx.x;
  if (bid < 8) {
    fps_body(x, bid, s1, coorq, s2, coorq2, outc, smem_raw);
  } else {
    int vb = bid - 8;
    fused_l1_body(x, w_in, b_in, w1, ymax1, ymin1, stats,
                  vb >> 7, (vb & 127)*16, smem_raw);
  }
}

// ---------------------------------------------------------------------------
// mega2: knn2 + knn3 + knn4 only.
// ---------------------------------------------------------------------------
__global__ __launch_bounds__(256) void mega2(
    const float* __restrict__ x, const float* __restrict__ coorq,
    const float* __restrict__ coorq2,
    int* __restrict__ idx2, int* __restrict__ idx3, int* __restrict__ idx4)
{
  __shared__ char smem_raw[32768] __attribute__((aligned(16)));
  const int bid = blockIdx.x;
  if (bid < 1024) {
    knn_body<2048>(coorq, 512, x, idx2, bid >> 7, (bid & 127)*4, (float*)smem_raw);
  } else if (bid < 2048) {
    int v = bid - 1024;
    knn_body<512>(coorq, 512, coorq, idx3, v >> 7, (v & 127)*4, (float*)smem_raw);
  } else {
    int v = bid - 2048;
    knn_body<512>(coorq2, 128, coorq, idx4, v >> 5, (v & 31)*4, (float*)smem_raw);
  }
}

// ---------------------------------------------------------------------------
// conv_p1mm (r13 verbatim, passing).
// ---------------------------------------------------------------------------
template<int C, int O, int NQ, int NKp, bool TN>
DI void conv_p1mm_body(
    const float* __restrict__ ymaxP, const float* __restrict__ yminP,
    const float* __restrict__ statsP,
    const float* __restrict__ gP, const float* __restrict__ beP,
    const int* __restrict__ qg, const int* __restrict__ knn_idx,
    const float* __restrict__ w,
    float* __restrict__ ymaxO, float* __restrict__ yminO, float* __restrict__ statsO,
    int nt, int g, int b, float* smem)
{
  constexpr int GRP = O/4;
  const float cntP = (float)((C/4) * NKp * 16);
  const int tid = threadIdx.x;
  float* sxq = smem;
  float* sw  = sxq + 16*C;
  float* dmu = sw + GRP*2*C;
  float* drs = dmu + C;
  float* dga = drs + C;
  float* dbe = dga + C;
  float* red = dbe + C;

  for (int i = tid; i < GRP*2*C; i += 256) sw[i] = w[(size_t)g*GRP*2*C + i];
  for (int i = tid; i < C; i += 256) {
    int gp = i / (C/4);
    float s0 = statsP[(b*4+gp)*2], s1v = statsP[(b*4+gp)*2+1];
    float mu = s0 / cntP;
    float var = fmaxf(s1v/cntP - mu*mu, 0.f);
    dmu[i] = mu; drs[i] = 1.f/sqrtf(var + 1e-5f);
    dga[i] = gP[i]; dbe[i] = beP[i];
  }
  __syncthreads();

  for (int i = tid; i < 16*C; i += 256) {
    int nn = i / C, ci = i % C;
    int q = nt*16 + nn;
    int src = qg ? qg[b*NQ + q] : q;
    float vmx = ymaxP[((size_t)b*NKp + src)*C + ci];
    float vmn = yminP[((size_t)b*NKp + src)*C + ci];
    float ga = dga[ci];
    float v = (ga >= 0.f) ? vmx : vmn;
    float a = ((v - dmu[ci])*drs[ci])*ga + dbe[ci];
    sxq[i] = a >= 0.f ? a : 0.2f*a;
  }
  __syncthreads();

  const int nloc = tid >> 4, kk = tid & 15;
  const int n = nt*16 + nloc;
  const int flat = n*16 + kk;
  const int r = flat / NQ, s = flat % NQ;
  const int nbr = knn_idx[((size_t)b*16 + r)*NQ + s];

  float xqv[C], h1[C];
  {
    const float4* xq4 = (const float4*)(sxq + nloc*C);
    const float4* mx4 = (const float4*)(ymaxP + ((size_t)b*NKp + nbr)*C);
    const float4* mn4 = (const float4*)(yminP + ((size_t)b*NKp + nbr)*C);
    const float4* pmu = (const float4*)dmu;
    const float4* prs = (const float4*)drs;
    const float4* pga = (const float4*)dga;
    const float4* pbe = (const float4*)dbe;
    #pragma unroll
    for (int c4 = 0; c4 < C/4; ++c4) {
      float4 a = xq4[c4], vx = mx4[c4], vn = mn4[c4];
      float4 mu = pmu[c4], rs = prs[c4], ga = pga[c4], be = pbe[c4];
      float v0 = (ga.x >= 0.f) ? vx.x : vn.x;
      float v1 = (ga.y >= 0.f) ? vx.y : vn.y;
      float v2 = (ga.z >= 0.f) ? vx.z : vn.z;
      float v3 = (ga.w >= 0.f) ? vx.w : vn.w;
      float f0 = ((v0 - mu.x)*rs.x)*ga.x + be.x; f0 = f0 >= 0.f ? f0 : 0.2f*f0;
      float f1 = ((v1 - mu.y)*rs.y)*ga.y + be.y; f1 = f1 >= 0.f ? f1 : 0.2f*f1;
      float f2 = ((v2 - mu.z)*rs.z)*ga.z + be.z; f2 = f2 >= 0.f ? f2 : 0.2f*f2;
      float f3 = ((v3 - mu.w)*rs.w)*ga.w + be.w; f3 = f3 >= 0.f ? f3 : 0.2f*f3;
      xqv[4*c4+0] = a.x; h1[4*c4+0] = f0 - a.x;
      xqv[4*c4+1] = a.y; h1[4*c4+1] = f1 - a.y;
      xqv[4*c4+2] = a.z; h1[4*c4+2] = f2 - a.z;
      xqv[4*c4+3] = a.w; h1[4*c4+3] = f3 - a.w;
    }
  }
  float lsum = 0.f, lsq = 0.f;
  for (int o = 0; o < GRP; ++o) {
    const float4* wr = (const float4*)(sw + o*2*C);
    float acc = 0.f;
    #pragma unroll
    for (int c4 = 0; c4 < C/4; ++c4) {
      float4 w4 = wr[c4];
      acc += w4.x*h1[4*c4] + w4.y*h1[4*c4+1] + w4.z*h1[4*c4+2] + w4.w*h1[4*c4+3];
    }
    #pragma unroll
    for (int c4 = 0; c4 < C/4; ++c4) {
      float4 w4 = wr[C/4 + c4];
      acc += w4.x*xqv[4*c4] + w4.y*xqv[4*c4+1] + w4.z*xqv[4*c4+2] + w4.w*xqv[4*c4+3];
    }
    float mx = acc, mn = acc;
    #pragma unroll
    for (int off = 1; off < 16; off <<= 1) {
      mx = fmaxf(mx, __shfl_xor(mx, off));
      mn = fminf(mn, __shfl_xor(mn, off));
    }
    if (kk == 0) {
      int og = g*GRP + o;
      size_t idx = TN ? (((size_t)b*NQ + n)*O + og) : (((size_t)b*O + og)*NQ + n);
      ymaxO[idx] = mx; yminO[idx] = mn;
    }
    lsum += acc; lsq += acc*acc;
  }
  #pragma unroll
  for (int off = 32; off; off >>= 1) {
    lsum += __shfl_xor(lsum, off);
    lsq  += __shfl_xor(lsq, off);
  }
  const int lane = tid & 63, wvid = tid >> 6;
  if (lane == 0) { red[wvid] = lsum; red[4+wvid] = lsq; }
  __syncthreads();
  if (tid == 0) {
    float s0  = (red[0]+red[1]) + (red[2]+red[3]);
    float s1v = (red[4]+red[5]) + (red[6]+red[7]);
    atomicAdd(statsO + ((size_t)b*4 + g)*2,     s0);
    atomicAdd(statsO + ((size_t)b*4 + g)*2 + 1, s1v);
  }
}

template<int C, int O, int NQ, int NKp, bool TN>
__global__ __launch_bounds__(256) void conv_p1mm(
    const float* __restrict__ ymaxP, const float* __restrict__ yminP,
    const float* __restrict__ statsP,
    const float* __restrict__ gP, const float* __restrict__ beP,
    const int* __restrict__ qg, const int* __restrict__ knn_idx,
    const float* __restrict__ w,
    float* __restrict__ ymaxO, float* __restrict__ yminO, float* __restrict__ statsO)
{
  __shared__ float smem_f[16*C + (O/4)*2*C + 4*C + 8];
  conv_p1mm_body<C, O, NQ, NKp, TN>(ymaxP, yminP, statsP, gP, beP, qg, knn_idx,
                                    w, ymaxO, yminO, statsO,
                                    blockIdx.x, blockIdx.y, blockIdx.z, smem_f);
}

// Final: L4 GN + lrelu from minmax.
__global__ __launch_bounds__(256) void l4fin(
    const float* __restrict__ ymax4, const float* __restrict__ ymin4,
    const float* __restrict__ stats4,
    const float* __restrict__ g4, const float* __restrict__ be4,
    float* __restrict__ f4)
{
  int t = blockIdx.x*256 + threadIdx.x;
  int b = t >> 14;
  int o = (t >> 7) & 127;
  int g = o >> 5;
  const float cnt = 32.f*128.f*16.f;
  float s0 = stats4[(b*4+g)*2], s1v = stats4[(b*4+g)*2+1];
  float mu = s0 / cnt;
  float var = fmaxf(s1v/cnt - mu*mu, 0.f);
  float rs = 1.f/sqrtf(var + 1e-5f);
  float ga = g4[o], be = be4[o];
  float v = (ga >= 0.f) ? ymax4[t] : ymin4[t];
  float a = ((v - mu)*rs)*ga + be;
  f4[t] = a >= 0.f ? a : 0.2f*a;
}

// ---------------------------------------------------------------------------
extern "C" void kernel_launch(void* const* d_in, const int* in_sizes, int n_in,
                              void* d_out, int out_size, void* d_ws, size_t ws_size,
                              hipStream_t stream)
{
  (void)in_sizes; (void)n_in; (void)out_size; (void)ws_size;
  const float* x    = (const float*)d_in[0];
  const float* w_in = (const float*)d_in[1];
  const float* b_in = (const float*)d_in[2];
  const float* w1   = (const float*)d_in[3];
  const float* g1   = (const float*)d_in[4];
  const float* be1  = (const float*)d_in[5];
  const float* w2   = (const float*)d_in[6];
  const float* g2   = (const float*)d_in[7];
  const float* be2  = (const float*)d_in[8];
  const float* w3   = (const float*)d_in[9];
  const float* g3   = (const float*)d_in[10];
  const float* be3  = (const float*)d_in[11];
  const float* w4   = (const float*)d_in[12];
  const float* g4   = (const float*)d_in[13];
  const float* be4  = (const float*)d_in[14];

  float* ws = (float*)d_ws;
  float* stats  = ws;                      // 256
  float* ymax1  = ws + 256;                // [8,2048,32]
  float* ymin1  = ws + 524544;
  int*   s1     = (int*)(ws + 1048832);    // [8,512]
  float* coorq  = ws + 1052928;            // [8,3,512]
  int*   idx2   = (int*)(ws + 1065216);    // [8,16,512]
  float* ymax2  = ws + 1130752;            // [8,512,64]
  float* ymin2  = ws + 1392896;
  int*   idx3   = (int*)(ws + 1655040);    // [8,16,512]
  float* ymax3  = ws + 1720576;            // [8,512,64]
  float* ymin3  = ws + 1982720;
  int*   s2     = (int*)(ws + 2244864);    // [8,128]
  float* coorq2 = ws + 2245888;            // [8,3,128]
  int*   idx4   = (int*)(ws + 2248960);    // [8,16,128]
  float* ymax4  = ws + 2265344;            // [8,128,128]
  float* ymin4  = ws + 2396416;

  float* outc = (float*)d_out;             // [8,3,128]
  float* f4   = (float*)d_out + 3072;      // [8,128,128]

  hipMemsetAsync(stats, 0, 256*sizeof(float), stream);

  mega1<<<dim3(1032), 256, 0, stream>>>(
      x, w_in, b_in, w1, ymax1, ymin1, stats, s1, coorq, s2, coorq2, outc);

  mega2<<<dim3(2304), 256, 0, stream>>>(x, coorq, coorq2, idx2, idx3, idx4);

  conv_p1mm<32, 64, 512, 2048, true><<<dim3(32, 4, 8), 256, 0, stream>>>(
      ymax1, ymin1, stats, g1, be1, s1, idx2, w2, ymax2, ymin2, stats + 64);

  conv_p1mm<64, 64, 512, 512, true><<<dim3(32, 4, 8), 256, 0, stream>>>(
      ymax2, ymin2, stats + 64, g2, be2, nullptr, idx3, w3, ymax3, ymin3, stats + 128);

  conv_p1mm<64, 128, 128, 512, false><<<dim3(8, 4, 8), 256, 0, stream>>>(
      ymax3, ymin3, stats + 128, g3, be3, s2, idx4, w4, ymax4, ymin4, stats + 192);

  l4fin<<<dim3(512), 256, 0, stream>>>(ymax4, ymin4, stats + 192, g4, be4, f4);
}